// Round 6
// baseline (361.444 us; speedup 1.0000x reference)
//
#include <hip/hip_runtime.h>
#include <hip/hip_bf16.h>
#include <math.h>

typedef __hip_bfloat16 bf16;

#define NRES 256
#define LC   32
#define HCH  128
#define ECH  64
#define NH   4
#define NCA  14
#define KNNK 8
#define DH   32
#define NKE  (NRES*KNNK)      // 2048
#define NEDGE (NKE+NRES)      // 2304
#define NE1  64
#define NROWS (NRES*NCA)      // 3584

// distance tables: nearest-neighbor, h=1/256, domain [0,12]
#define NT     3073
#define TSCALE 256.0f
#define DMAXT  12.0f

// ---- fp32 converted-input region offsets (floats) ----
#define O_RESH   0
#define O_RESX   458752
#define O_LPOS   469504
#define O_LFEAT  469888
#define O_LMASK  486272
#define O_LNG    486400
#define O_LNB    486528
#define O_LN1G   486656
#define O_LN1B   486784
#define O_WQ     486912
#define O_WK     503296
#define O_WV     519680
#define O_WKL    536064
#define O_WVL    552448
#define O_WO     568832
#define O_WOL    585216
#define O_WOL1   601600
#define O_TIW1   617984
#define O_TIB1   658944
#define O_TIW2   659072
#define O_TIB2   659200
#define O_SDW1   659204
#define O_SDB1   667396
#define O_SDW2   667524
#define O_SDB2   668036
#define O_SD1W1  668040
#define O_SD1B1  676232
#define O_SD1W2  676360
#define O_SD1B2  676872
#define TOTCVT   676876
#define CVT_RSV  676880

#define OUTX_OFF 458752
#define OUTL_OFF 469504

__constant__ int c_counts[21] = {14,5,11,8,8,6,9,9,4,10,8,8,9,8,11,7,6,7,14,12,7};

__device__ __forceinline__ float b2f(bf16 x){ return __bfloat162float(x); }
__device__ __forceinline__ float sspf(float x){
  return fmaxf(x,0.f) + log1pf(expf(-fabsf(x))) - 0.6931471805599453f;
}
__device__ __forceinline__ int ccount(int s){ return c_counts[s<0?0:(s>20?20:s)]; }
__device__ __forceinline__ void storeOut(void* out, int isbf, int idx, float v){
  if (isbf) ((bf16*)out)[idx] = __float2bfloat16(v);
  else      ((float*)out)[idx] = v;
}

// ---------------------------------------------------------------- kdet: detect input float dtype
__global__ __launch_bounds__(64) void kdet(const unsigned* __restrict__ resH_raw, int* __restrict__ flag)
{
  int tid = threadIdx.x;
  unsigned w = resH_raw[tid];
  unsigned lo = w & 0xFFFFu;
  int e = (lo >> 7) & 0xFF;
  int good = (lo == 0u) || (e >= 121 && e <= 133);
  unsigned long long m = __ballot(good);
  if (tid == 0) flag[0] = (__popcll(m) >= 40) ? 1 : 0;   // 1 = inputs are bf16
}

// ---------------------------------------------------------------- kcvt: all float inputs -> fp32 copies
__global__ __launch_bounds__(256) void kcvt(
    const int* __restrict__ flag,
    const void* s0,const void* s1,const void* s2,const void* s3,const void* s4,
    const void* s5,const void* s6,const void* s7,const void* s8,const void* s9,
    const void* s10,const void* s11,const void* s12,const void* s13,const void* s14,
    const void* s15,const void* s16,const void* s17,const void* s18,const void* s19,
    const void* s20,const void* s21,const void* s22,const void* s23,const void* s24,
    const void* s25,const void* s26,const void* s27,const void* s28,
    float* __restrict__ dst)
{
  int g = blockIdx.x*256 + threadIdx.x;
  if (g >= TOTCVT) return;
  const void* src; int l;
  if      (g < O_RESX ) { src=s0;  l=g; }
  else if (g < O_LPOS ) { src=s1;  l=g-O_RESX; }
  else if (g < O_LFEAT) { src=s2;  l=g-O_LPOS; }
  else if (g < O_LMASK) { src=s3;  l=g-O_LFEAT; }
  else if (g < O_LNG  ) { src=s4;  l=g-O_LMASK; }
  else if (g < O_LNB  ) { src=s5;  l=g-O_LNG; }
  else if (g < O_LN1G ) { src=s6;  l=g-O_LNB; }
  else if (g < O_LN1B ) { src=s7;  l=g-O_LN1G; }
  else if (g < O_WQ   ) { src=s8;  l=g-O_LN1B; }
  else if (g < O_WK   ) { src=s9;  l=g-O_WQ; }
  else if (g < O_WV   ) { src=s10; l=g-O_WK; }
  else if (g < O_WKL  ) { src=s11; l=g-O_WV; }
  else if (g < O_WVL  ) { src=s12; l=g-O_WKL; }
  else if (g < O_WO   ) { src=s13; l=g-O_WVL; }
  else if (g < O_WOL  ) { src=s14; l=g-O_WO; }
  else if (g < O_WOL1 ) { src=s15; l=g-O_WOL; }
  else if (g < O_TIW1 ) { src=s16; l=g-O_WOL1; }
  else if (g < O_TIB1 ) { src=s17; l=g-O_TIW1; }
  else if (g < O_TIW2 ) { src=s18; l=g-O_TIB1; }
  else if (g < O_TIB2 ) { src=s19; l=g-O_TIW2; }
  else if (g < O_SDW1 ) { src=s20; l=0; }
  else if (g < O_SDB1 ) { src=s21; l=g-O_SDW1; }
  else if (g < O_SDW2 ) { src=s22; l=g-O_SDB1; }
  else if (g < O_SDB2 ) { src=s23; l=g-O_SDW2; }
  else if (g < O_SD1W1) { src=s24; l=g-O_SDB2; }
  else if (g < O_SD1B1) { src=s25; l=g-O_SD1W1; }
  else if (g < O_SD1W2) { src=s26; l=g-O_SD1B1; }
  else if (g < O_SD1B2) { src=s27; l=g-O_SD1W2; }
  else                  { src=s28; l=g-O_SD1B2; }
  float v = (*flag) ? b2f(((const bf16*)src)[l]) : ((const float*)src)[l];
  dst[g] = v;
}

// ---------------------------------------------------------------- ktab: distance-function tables
__global__ __launch_bounds__(128) void ktab(const float* __restrict__ cvt,
    float* __restrict__ cT, float* __restrict__ sigT, float* __restrict__ sig1T)
{
  int i = blockIdx.x, o = threadIdx.x;
  __shared__ float dr[64];
  __shared__ float W[128*65];
  __shared__ float h1[128], h1b[128];
  float d = (float)i * (1.0f/256.0f);
  const float step = 10.0f/63.0f;
  const float coef = -0.5f/(step*step);
  if (o < 64){ float t = d - step*(float)o; dr[o] = expf(coef*t*t); }
  for (int idx=o; idx<8192; idx+=128){ int oo=idx>>6, k=idx&63; W[oo*65+k] = cvt[O_TIW1 + oo*320 + 256 + k]; }
  __syncthreads();
  {
    float c = cvt[O_TIB1+o];
    for (int k=0;k<64;k++) c += dr[k]*W[o*65+k];
    cT[i*128+o] = c;
  }
  __syncthreads();
  for (int idx=o; idx<8192; idx+=128){ int oo=idx>>6, k=idx&63; W[oo*65+k] = cvt[O_SDW1 + idx]; }
  __syncthreads();
  {
    float a = cvt[O_SDB1+o];
    for (int k=0;k<64;k++) a += dr[k]*W[o*65+k];
    h1[o] = fmaxf(a,0.f);
  }
  __syncthreads();
  for (int idx=o; idx<8192; idx+=128){ int oo=idx>>6, k=idx&63; W[oo*65+k] = cvt[O_SD1W1 + idx]; }
  __syncthreads();
  {
    float a2 = cvt[O_SD1B1+o];
    for (int k=0;k<64;k++) a2 += dr[k]*W[o*65+k];
    h1b[o] = fmaxf(a2,0.f);
  }
  __syncthreads();
  if (o < 8){
    int h = o & 3;
    const float* hh = (o<4)? h1 : h1b;
    int wbase = (o<4)? O_SDW2 : O_SD1W2;
    int bbase = (o<4)? O_SDB2 : O_SD1B2;
    float s = cvt[bbase + h];
    for (int k=0;k<128;k++) s += hh[k]*cvt[wbase + h*128 + k];
    if (o<4) sigT[i*4+h] = s; else sig1T[i*4+h] = s;
  }
}

// ---------------------------------------------------------------- k0: transpose weights + inv_row
__global__ __launch_bounds__(256) void k0_prep(
    const float* __restrict__ cvt, const int* __restrict__ row1,
    float* __restrict__ wt, int* __restrict__ inv_row)
{
  int bid = blockIdx.x, tid = threadIdx.x;
  if (bid == 640){
    if (tid < NRES) inv_row[tid] = -1;
    __syncthreads();
    if (tid < NE1) inv_row[row1[tid] & 255] = tid;
    return;
  }
  int gid = bid*256 + tid;
  int m = gid >> 14;
  int j = gid & 16383;
  int o = j >> 7, c = j & 127;
  float v;
  switch(m){
    case 0: v = cvt[O_WQ  + j]; break;
    case 1: v = cvt[O_WK  + j]; break;
    case 2: v = cvt[O_WV  + j]; break;
    case 3: v = cvt[O_WO  + j]; break;
    case 4: v = cvt[O_WKL + j]; break;
    case 5: v = cvt[O_WVL + j]; break;
    case 6: v = cvt[O_WOL + j]; break;
    case 7: v = cvt[O_WOL1+ j]; break;
    case 8: v = cvt[O_TIW1 + o*320 + c]; break;
    default:v = cvt[O_TIW1 + o*320 + 128 + c]; break;
  }
  wt[m*16384 + c*128 + o] = v;
}

// ------------------------------------------------- kProj: LN + {Q,K,V} (+TQ/TK chained) per 16-row tile
// grid (224, 3): m=0 -> Q then TQ; m=1 -> K then TK; m=2 -> V only.
__global__ __launch_bounds__(256) void kProj(
    const float* __restrict__ cvt, const float* __restrict__ wt,
    float* __restrict__ resHn, float* __restrict__ Qw, float* __restrict__ Kw,
    float* __restrict__ Vw, float* __restrict__ TQw, float* __restrict__ TKw)
{
  int m = blockIdx.y;
  int rt = blockIdx.x * 16;
  int tid = threadIdx.x;
  __shared__ float Xs[16*129];
  for (int i=tid; i<16*128; i+=256){
    int r=i>>7, c=i&127;
    Xs[r*129+c] = cvt[O_RESH + (rt+r)*HCH + c];
  }
  __syncthreads();
  {
    // LN: 4 rows per wave, 16 lanes per row, 8 cols per lane; xor-shuffles stay in 16-lane group
    int wave = tid>>6, lane = tid&63;
    int r = wave*4 + (lane>>4);
    int cb = lane & 15;
    float s=0;
    #pragma unroll
    for (int j=0;j<8;j++) s += Xs[r*129 + cb + 16*j];
    #pragma unroll
    for (int off=1; off<16; off<<=1) s += __shfl_xor(s, off);
    float mu = s*(1.f/HCH);
    float q=0;
    #pragma unroll
    for (int j=0;j<8;j++){ float dv = Xs[r*129+cb+16*j]-mu; q += dv*dv; }
    #pragma unroll
    for (int off=1; off<16; off<<=1) q += __shfl_xor(q, off);
    float inv = rsqrtf(q*(1.f/HCH) + 1e-5f);
    #pragma unroll
    for (int j=0;j<8;j++){
      int c = cb + 16*j;
      float xh = (Xs[r*129+c]-mu)*inv*cvt[O_LNG+c] + cvt[O_LNB+c];
      Xs[r*129+c] = xh;
      if (m==0) resHn[(rt+r)*HCH+c] = xh;
    }
  }
  __syncthreads();
  int tc = (tid & 31) * 4;
  int tr = (tid >> 5) * 2;
  const float* W = wt + m*16384;
  float a00=0,a01=0,a02=0,a03=0, a10=0,a11=0,a12=0,a13=0;
  for (int c=0;c<HCH;c++){
    float4 w4 = *(const float4*)(W + c*128 + tc);
    float x0 = Xs[tr*129 + c];
    float x1 = Xs[(tr+1)*129 + c];
    a00 += x0*w4.x; a01 += x0*w4.y; a02 += x0*w4.z; a03 += x0*w4.w;
    a10 += x1*w4.x; a11 += x1*w4.y; a12 += x1*w4.z; a13 += x1*w4.w;
  }
  float* out = (m==0)? Qw : (m==1)? Kw : Vw;
  *(float4*)(out + (rt+tr  )*HCH + tc) = make_float4(a00,a01,a02,a03);
  *(float4*)(out + (rt+tr+1)*HCH + tc) = make_float4(a10,a11,a12,a13);
  if (m == 2) return;
  __syncthreads();
  Xs[tr*129+tc]=a00; Xs[tr*129+tc+1]=a01; Xs[tr*129+tc+2]=a02; Xs[tr*129+tc+3]=a03;
  Xs[(tr+1)*129+tc]=a10; Xs[(tr+1)*129+tc+1]=a11; Xs[(tr+1)*129+tc+2]=a12; Xs[(tr+1)*129+tc+3]=a13;
  __syncthreads();
  const float* W2 = wt + (8+m)*16384;
  a00=0;a01=0;a02=0;a03=0; a10=0;a11=0;a12=0;a13=0;
  for (int c=0;c<HCH;c++){
    float4 w4 = *(const float4*)(W2 + c*128 + tc);
    float x0 = Xs[tr*129 + c];
    float x1 = Xs[(tr+1)*129 + c];
    a00 += x0*w4.x; a01 += x0*w4.y; a02 += x0*w4.z; a03 += x0*w4.w;
    a10 += x1*w4.x; a11 += x1*w4.y; a12 += x1*w4.z; a13 += x1*w4.w;
  }
  float* out2 = m ? TKw : TQw;
  *(float4*)(out2 + (rt+tr  )*HCH + tc) = make_float4(a00,a01,a02,a03);
  *(float4*)(out2 + (rt+tr+1)*HCH + tc) = make_float4(a10,a11,a12,a13);
}

// ------------------------------------------------- k2: KNN — one wave per residue, shuffle-only
__global__ __launch_bounds__(256) void k2_knn(
    const float* __restrict__ cvt, const int* __restrict__ batch, int* __restrict__ nbr)
{
  int wave = threadIdx.x>>6, lane = threadIdx.x&63;
  int n = blockIdx.x*4 + wave;
  float cx = cvt[O_RESX+(n*NCA+1)*3+0];
  float cy = cvt[O_RESX+(n*NCA+1)*3+1];
  float cz = cvt[O_RESX+(n*NCA+1)*3+2];
  int bn = batch[n];
  float d2v[4]; int idv[4];
  #pragma unroll
  for (int t=0;t<4;t++){
    int j = lane + 64*t;
    float jx = cvt[O_RESX+(j*NCA+1)*3+0];
    float jy = cvt[O_RESX+(j*NCA+1)*3+1];
    float jz = cvt[O_RESX+(j*NCA+1)*3+2];
    float dx=cx-jx, dy=cy-jy, dz=cz-jz;
    float d2 = dx*dx+dy*dy+dz*dz;
    bool bad = (batch[j]!=bn) || (j==n);
    d2v[t] = bad ? INFINITY : d2;
    idv[t] = j;
  }
  for (int k=0;k<KNNK;k++){
    float dm = d2v[0]; int im = idv[0];
    #pragma unroll
    for (int t=1;t<4;t++)
      if (d2v[t]<dm || (d2v[t]==dm && idv[t]<im)){ dm=d2v[t]; im=idv[t]; }
    #pragma unroll
    for (int off=1; off<64; off<<=1){
      float dn = __shfl_xor(dm, off);
      int   in = __shfl_xor(im, off);
      if (dn<dm || (dn==dm && in<im)){ dm=dn; im=in; }
    }
    if (lane==0) nbr[n*KNNK+k] = im;
    #pragma unroll
    for (int t=0;t<4;t++) if (idv[t]==im) d2v[t] = INFINITY;
  }
}

// ------------------------------------------------- k5: ligand LN + Kl/Vl projections
__global__ __launch_bounds__(128) void k5_ligproj(
    const float* __restrict__ cvt, const float* __restrict__ wt, float* __restrict__ lf,
    float* __restrict__ Klw, float* __restrict__ Vlw)
{
  int rb = blockIdx.x, tid = threadIdx.x;
  __shared__ float x[HCH];
  __shared__ float sred[2];
  float v = cvt[O_LFEAT + rb*HCH + tid];
  float s=v;
  for (int off=1; off<64; off<<=1) s += __shfl_xor(s, off);
  if ((tid&63)==0) sred[tid>>6]=s;
  __syncthreads();
  float mu=(sred[0]+sred[1])*(1.f/HCH);
  __syncthreads();
  float d=v-mu; s=d*d;
  for (int off=1; off<64; off<<=1) s += __shfl_xor(s, off);
  if ((tid&63)==0) sred[tid>>6]=s;
  __syncthreads();
  float var=(sred[0]+sred[1])*(1.f/HCH);
  float xh = d*rsqrtf(var+1e-5f)*cvt[O_LN1G+tid] + cvt[O_LN1B+tid];
  x[tid]=xh; lf[rb*HCH+tid]=xh;
  __syncthreads();
  const float* WKlt = wt + 4*16384;
  const float* WVlt = wt + 5*16384;
  float aK=0.f, aV=0.f;
  for (int c=0;c<HCH;c++){
    float xc=x[c];
    aK += xc*WKlt[c*128+tid];
    aV += xc*WVlt[c*128+tid];
  }
  Klw[rb*HCH+tid]=aK; Vlw[rb*HCH+tid]=aV;
}

// ------------------------------------------------- k3: fused residue-edge (logits + softmax + r/aV/dX)
__global__ __launch_bounds__(256) void k3_edge(
    const float* __restrict__ cvt, const int* __restrict__ res_S, const int* __restrict__ nbr,
    const float* __restrict__ Qw, const float* __restrict__ Kw,
    const float* __restrict__ TQw, const float* __restrict__ TKw,
    const float* __restrict__ Vw, const float* __restrict__ cT, const float* __restrict__ sigT,
    float* __restrict__ r_ws, float* __restrict__ aVe, float* __restrict__ dXe)
{
  __shared__ float Bq[1848], Bk[1848], Tq[1848], Tk[1848], Vc[1848];   // stride 132
  __shared__ float LG[784], FR[196];
  __shared__ float tw2s[128], tb2s[1], Xr[42], Xc[42], amr[14], amc[14], rpart[56], cnts[2];
  int e = blockIdx.x, tid = threadIdx.x;
  int rr, cc;
  if (e < NKE){ rr = e >> 3; cc = nbr[e] & 255; } else { rr = e - NKE; cc = rr; }

  for (int i=tid;i<NCA*HCH;i+=256){
    int p=i>>7, c=i&127;
    Bq[p*132+c]=Qw[rr*1792+i];  Bk[p*132+c]=Kw[cc*1792+i];
    Tq[p*132+c]=TQw[rr*1792+i]; Tk[p*132+c]=TKw[cc*1792+i];
    Vc[p*132+c]=Vw[cc*1792+i];
  }
  if (tid < 128) tw2s[tid]=cvt[O_TIW2+tid];
  if (tid == 128) tb2s[0]=cvt[O_TIB2];
  if (tid >= 136 && tid < 178){
    int i=tid-136; int p=i/3, jx=i%3;
    Xr[i] = cvt[O_RESX+(rr*NCA+p)*3+jx];
    Xc[i] = cvt[O_RESX+(cc*NCA+p)*3+jx];
  }
  if (tid >= 242 && tid < 242+NCA){
    int p=tid-242;
    amr[p] = (p < ccount(res_S[rr])) ? 1.f : 0.f;
    amc[p] = (p < ccount(res_S[cc])) ? 1.f : 0.f;
  }
  __syncthreads();

  if (tid < 196){
    int p = tid/14, q = tid%14;
    float dx=Xr[p*3]-Xc[q*3], dy=Xr[p*3+1]-Xc[q*3+1], dz=Xr[p*3+2]-Xc[q*3+2];
    float d = sqrtf(fmaxf(dx*dx+dy*dy+dz*dz, 1e-12f));
    int i0 = (int)(fminf(d, DMAXT)*TSCALE + 0.5f);
    float4 sg = ((const float4*)sigT)[i0];
    const float4* crow = (const float4*)(cT + i0*128);
    float fa = tb2s[0];
    #pragma unroll 8
    for (int j=0;j<32;j++){
      float4 cb = crow[j];
      int o = 4*j;
      fa += fmaxf(Tq[p*132+o  ]+Tk[q*132+o  ]+cb.x, 0.f)*tw2s[o  ];
      fa += fmaxf(Tq[p*132+o+1]+Tk[q*132+o+1]+cb.y, 0.f)*tw2s[o+1];
      fa += fmaxf(Tq[p*132+o+2]+Tk[q*132+o+2]+cb.z, 0.f)*tw2s[o+2];
      fa += fmaxf(Tq[p*132+o+3]+Tk[q*132+o+3]+cb.w, 0.f)*tw2s[o+3];
    }
    float qk0=0,qk1=0,qk2=0,qk3=0;
    #pragma unroll
    for (int dd=0;dd<DH;dd++){
      qk0 += Bq[p*132+dd]   *Bk[q*132+dd];
      qk1 += Bq[p*132+32+dd]*Bk[q*132+32+dd];
      qk2 += Bq[p*132+64+dd]*Bk[q*132+64+dd];
      qk3 += Bq[p*132+96+dd]*Bk[q*132+96+dd];
    }
    const float isq = 0.17677669529663687f;
    LG[0*196+tid] = qk0*isq + sg.x;
    LG[1*196+tid] = qk1*isq + sg.y;
    LG[2*196+tid] = qk2*isq + sg.z;
    LG[3*196+tid] = qk3*isq + sg.w;
    FR[tid] = fa;
  }
  __syncthreads();

  if (tid < 56){
    int h=tid/14, pp=tid%14;
    float ap = amr[pp];
    float row[NCA];
    float s=0;
    #pragma unroll
    for (int qq=0;qq<NCA;qq++){ row[qq]=LG[h*196+pp*14+qq]; s += row[qq]*amc[qq]; }
    rpart[h*14+pp] = s*ap;
    float m=-INFINITY;
    #pragma unroll
    for (int qq=0;qq<NCA;qq++) m=fmaxf(m,row[qq]);
    float sum=0;
    #pragma unroll
    for (int qq=0;qq<NCA;qq++){ row[qq]=expf(row[qq]-m); sum+=row[qq]; }
    float inv=1.f/sum, s2=0;
    #pragma unroll
    for (int qq=0;qq<NCA;qq++){ row[qq]=row[qq]*inv*ap*amc[qq]; s2+=row[qq]; }
    float inv2=1.f/(s2+1e-7f);
    #pragma unroll
    for (int qq=0;qq<NCA;qq++) LG[h*196+pp*14+qq]=row[qq]*inv2;
  }
  if (tid == 56){
    float sr=0, sc=0;
    for (int i=0;i<NCA;i++){ sr+=amr[i]; sc+=amc[i]; }
    cnts[0]=sr; cnts[1]=sc;
  }
  __syncthreads();
  if (tid < NH){
    float s=0;
    for (int pp=0;pp<NCA;pp++) s += rpart[tid*14+pp];
    r_ws[e*NH+tid] = s/(cnts[0]*cnts[1]);
  }
  if (tid < 196){
    int p=tid/14, q=tid%14;
    float ma = 0.25f*(LG[p*14+q] + LG[196+p*14+q] + LG[392+p*14+q] + LG[588+p*14+q]);
    FR[tid] *= ma;
  }
  __syncthreads();
  if (tid < NCA){
    int pp=tid;
    float ax=0, ay=0, az=0;
    #pragma unroll
    for (int qq=0;qq<NCA;qq++){
      float dx=Xr[pp*3]-Xc[qq*3], dy=Xr[pp*3+1]-Xc[qq*3+1], dz=Xr[pp*3+2]-Xc[qq*3+2];
      float nrm = sqrtf(fmaxf(dx*dx+dy*dy+dz*dz,1e-12f));
      float sc = FR[pp*14+qq]/(nrm+1e-5f);
      ax += sc*dx; ay += sc*dy; az += sc*dz;
    }
    dXe[(e*NCA+pp)*3+0]=ax; dXe[(e*NCA+pp)*3+1]=ay; dXe[(e*NCA+pp)*3+2]=az;
  }
  #pragma unroll
  for (int rep=0;rep<7;rep++){
    int jdx = rep*256 + tid;
    int h = jdx/448, rem = jdx%448;
    int pp = rem>>5, dd = rem&31;
    float acc=0;
    #pragma unroll
    for (int qq=0;qq<NCA;qq++) acc += LG[h*196+pp*14+qq]*Vc[qq*132 + h*32 + dd];
    aVe[e*1792 + jdx] = acc;
  }
}

// ------------------------------------------------- k4: per-residue beta + updH + WO + dX
__global__ __launch_bounds__(128) void k4_agg(
    const float* __restrict__ cvt, const int* __restrict__ res_S, const int* __restrict__ inv_row,
    const float* __restrict__ r_ws, const float* __restrict__ aVe, const float* __restrict__ dXe,
    const float* __restrict__ resHn, const float* __restrict__ wt, const int* __restrict__ flag,
    float* __restrict__ resH2, float* __restrict__ resX2, void* __restrict__ d_out)
{
  int n = blockIdx.x, tid = threadIdx.x;
  __shared__ float beta[9][NH];
  __shared__ float betam[9];
  __shared__ float Xs[NCA][HCH];
  if (tid < NH){
    int h = tid;
    float rv[9], m=-INFINITY;
    #pragma unroll
    for (int k=0;k<9;k++){
      int ek = (k<KNNK)? n*KNNK+k : NKE+n;
      rv[k] = r_ws[ek*NH+h];
      m = fmaxf(m, rv[k]);
    }
    float s=0;
    #pragma unroll
    for (int k=0;k<9;k++){ rv[k]=expf(rv[k]-m); s+=rv[k]; }
    #pragma unroll
    for (int k=0;k<9;k++) beta[k][h]=rv[k]/s;
  }
  __syncthreads();
  if (tid < 9) betam[tid] = 0.25f*(beta[tid][0]+beta[tid][1]+beta[tid][2]+beta[tid][3]);
  int h = tid>>5, dd = tid&31;
  float bh[9];
  #pragma unroll
  for (int k=0;k<9;k++) bh[k]=beta[k][h];
  for (int p=0;p<NCA;p++){
    float u=0;
    #pragma unroll
    for (int k=0;k<9;k++){
      int ek = (k<KNNK)? n*KNNK+k : NKE+n;
      u += bh[k]*aVe[ek*1792 + h*448 + p*32 + dd];
    }
    Xs[p][tid] = sspf(u);
  }
  __syncthreads();
  const float* WOt = wt + 3*16384;
  float acc[NCA];
  #pragma unroll
  for (int p=0;p<NCA;p++) acc[p]=0.f;
  for (int c=0;c<HCH;c++){
    float w = WOt[c*128+tid];
    #pragma unroll
    for (int p=0;p<NCA;p++) acc[p] += Xs[p][c]*w;
  }
  int cnt = ccount(res_S[n]);
  for (int p=0;p<NCA;p++){
    float am = (p<cnt)?1.f:0.f;
    float outv = (resHn[(n*NCA+p)*HCH+tid] + acc[p])*am;
    resH2[(n*NCA+p)*HCH+tid] = outv;
  }
  if (tid < NCA*3){
    int isbf = *flag;
    int p=tid/3, jx=tid%3;
    float s=0;
    #pragma unroll
    for (int k=0;k<9;k++){
      int ek=(k<KNNK)? n*KNNK+k : NKE+n;
      s += betam[k]*dXe[(ek*NCA+p)*3+jx];
    }
    float base = cvt[O_RESX+(n*NCA+p)*3+jx];
    float v = (inv_row[n]>=0) ? base + fminf(fmaxf(s,-3.f),3.f) : base;
    resX2[(n*NCA+p)*3+jx] = v;
    storeOut(d_out, isbf, OUTX_OFF + (n*NCA+p)*3+jx, v);
  }
}

// ------------------------------------------------- k6: fused ligand-edge (logits + softmaxes + aVr/aVlg)
__global__ __launch_bounds__(256) void k6_lig(
    const float* __restrict__ cvt, const int* __restrict__ res_S,
    const int* __restrict__ row1, const int* __restrict__ col1,
    const float* __restrict__ resX2, const float* __restrict__ Qw, const float* __restrict__ Klw,
    const float* __restrict__ Vw, const float* __restrict__ Vlw, const float* __restrict__ sig1T,
    float* __restrict__ r1_ws, float* __restrict__ aVr, float* __restrict__ aVlg)
{
  __shared__ __align__(16) float S[10042];
  float* Bq  = S;            // 1848 (phase A)      | LG aliases S+0   (1792, phase B)
  float* Bk  = S + 1848;     // 4256 = 32*133       | Vl aliases S+1848 (4224, phase B)
  float* LG  = S;
  float* Vl  = S + 1848;
  float* ALs = S + 6104;     // 1792
  float* Vr  = S + 7896;     // 1848
  float* EX  = S + 9744;
  float* Xr = EX;            // 42
  float* Lp = EX + 42;       // 96
  float* amr = EX + 138;     // 14
  float* lm  = EX + 152;     // 32
  float* s2r = EX + 184;     // 56
  float* rpart = EX + 240;   // 56
  float* cnts  = EX + 296;   // 2
  int e = blockIdx.x, tid = threadIdx.x;
  int rr = row1[e] & 255, cb = col1[e] & 3;

  for (int i=tid;i<NCA*HCH;i+=256){ int p=i>>7,c=i&127; Bq[p*132+c]=Qw[rr*1792+i]; Vr[p*132+c]=Vw[rr*1792+i]; }
  for (int i=tid;i<LC*HCH;i+=256){ int q=i>>7,c=i&127; Bk[q*133+c]=Klw[cb*LC*HCH+i]; }
  if (tid >= 8 && tid < 50){ int i=tid-8; int p=i/3,jx=i%3; Xr[i]=resX2[(rr*NCA+p)*3+jx]; }
  if (tid >= 64 && tid < 160){ int i=tid-64; int q=i/3,jx=i%3; Lp[i]=cvt[O_LPOS+(cb*LC+q)*3+jx]; }
  if (tid >= 160 && tid < 160+NCA) amr[tid-160]=((tid-160) < ccount(res_S[rr]))?1.f:0.f;
  if (tid >= 192 && tid < 224) lm[tid-192]=cvt[O_LMASK + cb*LC + tid-192];
  __syncthreads();

  float l0[2][4];
  int npair = (tid < 192) ? 2 : 1;
  for (int w=0; w<npair; w++){
    int pair = tid + w*256;
    int p = pair>>5, q = pair&31;
    float dx=Xr[p*3]-Lp[q*3], dy=Xr[p*3+1]-Lp[q*3+1], dz=Xr[p*3+2]-Lp[q*3+2];
    float d = sqrtf(fmaxf(dx*dx+dy*dy+dz*dz,1e-12f));
    int i0 = (int)(fminf(d, DMAXT)*TSCALE + 0.5f);
    float4 sg = ((const float4*)sig1T)[i0];
    float q0=0,q1=0,q2=0,q3=0;
    #pragma unroll
    for (int dd=0;dd<DH;dd++){
      q0 += Bq[p*132+dd]   *Bk[q*133+dd];
      q1 += Bq[p*132+32+dd]*Bk[q*133+32+dd];
      q2 += Bq[p*132+64+dd]*Bk[q*133+64+dd];
      q3 += Bq[p*132+96+dd]*Bk[q*133+96+dd];
    }
    const float isq=0.17677669529663687f;
    l0[w][0]=q0*isq+sg.x; l0[w][1]=q1*isq+sg.y; l0[w][2]=q2*isq+sg.z; l0[w][3]=q3*isq+sg.w;
  }
  __syncthreads();   // all Bq/Bk reads done; aliases now safe
  for (int w=0; w<npair; w++){
    int pair = tid + w*256;
    LG[0*448+pair]=l0[w][0]; LG[1*448+pair]=l0[w][1]; LG[2*448+pair]=l0[w][2]; LG[3*448+pair]=l0[w][3];
  }
  for (int i=tid;i<LC*HCH;i+=256){ int q=i>>7,c=i&127; Vl[q*132+c]=Vlw[cb*LC*HCH+i]; }
  __syncthreads();

  if (tid < 56){
    int h=tid/14, pp=tid%14;
    float ap=amr[pp];
    float s=0, m=-INFINITY;
    for (int qq=0;qq<LC;qq++){ float v=LG[h*448+pp*32+qq]; s+=v*lm[qq]; m=fmaxf(m,v); }
    rpart[h*14+pp]=s*ap;
    float sum=0;
    for (int qq=0;qq<LC;qq++) sum+=expf(LG[h*448+pp*32+qq]-m);
    float inv=1.f/sum, s2=0;
    for (int qq=0;qq<LC;qq++) s2 += expf(LG[h*448+pp*32+qq]-m)*inv*ap*lm[qq];
    s2r[h*14+pp] = s2/(s2+1e-7f);
  }
  if (tid==56){
    float sr=0,sl=0;
    for(int i=0;i<NCA;i++) sr+=amr[i];
    for(int i=0;i<LC;i++) sl+=lm[i];
    cnts[0]=sr; cnts[1]=sl;
  }
  __syncthreads();
  if (tid < NH){
    float s=0; for (int pp=0;pp<NCA;pp++) s+=rpart[tid*14+pp];
    r1_ws[e*NH+tid]=s/(cnts[0]*cnts[1]);
  }
  if (tid < NH*LC){
    int h=tid>>5, qq=tid&31;
    float m=-INFINITY;
    for (int pp=0;pp<NCA;pp++) m=fmaxf(m,LG[h*448+pp*32+qq]);
    float sum=0;
    for (int pp=0;pp<NCA;pp++) sum+=expf(LG[h*448+pp*32+qq]-m);
    float inv=1.f/sum;
    float lq=lm[qq];
    for (int pp=0;pp<NCA;pp++){
      float a=expf(LG[h*448+pp*32+qq]-m)*inv*amr[pp]*lq;
      ALs[h*448+pp*32+qq]=a/(s2r[h*14+pp]+1e-7f);
    }
  }
  __syncthreads();
  if (tid < 56){
    int h=tid/14, pp=tid%14;
    float ap=amr[pp];
    float m=-INFINITY;
    for (int qq=0;qq<LC;qq++) m=fmaxf(m,LG[h*448+pp*32+qq]);
    float row[LC];
    float sum=0;
    for (int qq=0;qq<LC;qq++){ row[qq]=expf(LG[h*448+pp*32+qq]-m); sum+=row[qq]; }
    float inv=1.f/sum, s2=0;
    for (int qq=0;qq<LC;qq++){ row[qq]=row[qq]*inv*ap*lm[qq]; s2+=row[qq]; }
    float inv2=1.f/(s2+1e-7f);
    for (int qq=0;qq<LC;qq++) LG[h*448+pp*32+qq]=row[qq]*inv2;
  }
  __syncthreads();
  for (int j=tid;j<NH*NCA*DH;j+=256){
    int h=j/448, rem=j%448, pp=rem>>5, dd=rem&31;
    float acc=0;
    #pragma unroll
    for (int qq=0;qq<LC;qq++) acc += LG[h*448+pp*32+qq]*Vl[qq*132+h*32+dd];
    aVr[e*1792+j]=acc;
  }
  for (int j=tid;j<NH*LC*DH;j+=256){
    int h=j>>10, rem=j&1023, qq=rem>>5, dd=rem&31;
    float acc=0;
    #pragma unroll
    for (int pp=0;pp<NCA;pp++) acc += ALs[h*448+pp*32+qq]*Vr[pp*132+h*32+dd];
    aVlg[e*4096+j]=acc;
  }
}

// ------------------------------------------------- k7: finalize res_H3
__global__ __launch_bounds__(128) void k7_finalH(
    const int* __restrict__ inv_row, const int* __restrict__ res_S,
    const float* __restrict__ resH2, const float* __restrict__ aVr,
    const float* __restrict__ wt, const int* __restrict__ flag, void* __restrict__ d_out)
{
  int n=blockIdx.x, tid=threadIdx.x;
  int e = inv_row[n];
  __shared__ float G[NCA][HCH];
  if (e>=0){
    for (int j=tid;j<NCA*HCH;j+=128){
      int h=j/448, rem=j%448, pp=rem>>5, dd=rem&31;
      G[pp][h*DH+dd] = sspf(aVr[e*1792+j]);
    }
  }
  __syncthreads();
  float acc[NCA];
  #pragma unroll
  for (int p=0;p<NCA;p++) acc[p]=0.f;
  if (e>=0){
    const float* WOlt = wt + 6*16384;
    for (int c=0;c<HCH;c++){
      float w=WOlt[c*128+tid];
      #pragma unroll
      for (int p=0;p<NCA;p++) acc[p]+=G[p][c]*w;
    }
  }
  int cnt=ccount(res_S[n]);
  int isbf = *flag;
  for (int p=0;p<NCA;p++){
    float am=(p<cnt)?1.f:0.f;
    float v=(resH2[(n*NCA+p)*HCH+tid]+acc[p])*am;
    storeOut(d_out, isbf, (n*NCA+p)*HCH+tid, v);
  }
}

// ------------------------------------------------- k8: beta1 + updL + WOl1 -> lf2
__global__ __launch_bounds__(128) void k8_lf2(
    const int* __restrict__ col1, const float* __restrict__ r1_ws, const float* __restrict__ aVlg,
    const float* __restrict__ lf, const float* __restrict__ wt, const int* __restrict__ flag,
    void* __restrict__ d_out)
{
  int rb=blockIdx.x, tid=threadIdx.x;
  int b=rb>>5, q=rb&31;
  __shared__ float bw[NE1][NH];
  __shared__ float xs[HCH];
  if (tid<NH){
    int h=tid;
    float m=-INFINITY;
    for (int e=0;e<NE1;e++) if ((col1[e]&3)==b) m=fmaxf(m, r1_ws[e*NH+h]);
    float s=0;
    for (int e=0;e<NE1;e++) if ((col1[e]&3)==b) s+=expf(r1_ws[e*NH+h]-m);
    for (int e=0;e<NE1;e++) bw[e][h] = ((col1[e]&3)==b)? expf(r1_ws[e*NH+h]-m)/s : 0.f;
  }
  __syncthreads();
  int h=tid>>5, dd=tid&31;
  float u=0;
  for (int e=0;e<NE1;e++) u += bw[e][h]*aVlg[e*4096 + h*1024 + q*32 + dd];
  xs[tid]=sspf(u);
  __syncthreads();
  const float* WOl1t = wt + 7*16384;
  float acc=0;
  for (int c=0;c<HCH;c++) acc += xs[c]*WOl1t[c*128+tid];
  float v = lf[rb*HCH+tid] + acc;
  storeOut(d_out, *flag, OUTL_OFF + rb*HCH+tid, v);
}

// ================================================================ launch
extern "C" void kernel_launch(void* const* d_in, const int* in_sizes, int n_in,
                              void* d_out, int out_size, void* d_ws, size_t ws_size,
                              hipStream_t stream)
{
  const int* res_S = (const int*)d_in[29];
  const int* batch = (const int*)d_in[30];
  const int* row1  = (const int*)d_in[32];
  const int* col1  = (const int*)d_in[33];

  float* wsf = (float*)d_ws;
  size_t o = 0;
  int*   flag    = (int*)(wsf + o); o += 4;
  float* cvt     = wsf + o; o += CVT_RSV;
  float* wt      = wsf + o; o += 10*16384;
  int*   inv_row = (int*)(wsf + o); o += 256;
  int*   nbr     = (int*)(wsf + o); o += NRES*KNNK;
  float* resHn   = wsf + o; o += NROWS*HCH;
  float* Qw      = wsf + o; o += NROWS*HCH;
  float* Kw      = wsf + o; o += NROWS*HCH;
  float* Vw      = wsf + o; o += NROWS*HCH;
  float* TQw     = wsf + o; o += NROWS*HCH;
  float* TKw     = wsf + o; o += NROWS*HCH;
  float* r_ws    = wsf + o; o += NEDGE*NH;
  float* aVe     = wsf + o; o += (size_t)NEDGE*1792;
  float* dXe     = wsf + o; o += NEDGE*NCA*3;
  float* resH2   = wsf + o; o += NROWS*HCH;
  float* resX2   = wsf + o; o += NRES*NCA*3;
  float* lf      = wsf + o; o += 4*LC*HCH;
  float* Klw     = wsf + o; o += 4*LC*HCH;
  float* Vlw     = wsf + o; o += 4*LC*HCH;
  float* r1w     = wsf + o; o += NE1*NH;
  float* aVrw    = wsf + o; o += NE1*1792;
  float* aVlgw   = wsf + o; o += NE1*4096;
  float* cT      = wsf + o; o += (size_t)NT*128;
  float* sigT    = wsf + o; o += NT*4;
  float* sig1T   = wsf + o; o += NT*4;

  kdet<<<1, 64, 0, stream>>>((const unsigned*)d_in[0], flag);
  kcvt<<<(TOTCVT+255)/256, 256, 0, stream>>>(flag,
      d_in[0],d_in[1],d_in[2],d_in[3],d_in[4],d_in[5],d_in[6],d_in[7],d_in[8],
      d_in[9],d_in[10],d_in[11],d_in[12],d_in[13],d_in[14],d_in[15],d_in[16],
      d_in[17],d_in[18],d_in[19],d_in[20],d_in[21],d_in[22],d_in[23],d_in[24],
      d_in[25],d_in[26],d_in[27],d_in[28], cvt);
  ktab<<<NT, 128, 0, stream>>>(cvt, cT, sigT, sig1T);
  k0_prep<<<641, 256, 0, stream>>>(cvt, row1, wt, inv_row);
  kProj<<<dim3(NROWS/16, 3), 256, 0, stream>>>(cvt, wt, resHn, Qw, Kw, Vw, TQw, TKw);
  k2_knn<<<NRES/4, 256, 0, stream>>>(cvt, batch, nbr);
  k5_ligproj<<<4*LC, 128, 0, stream>>>(cvt, wt, lf, Klw, Vlw);
  k3_edge<<<NEDGE, 256, 0, stream>>>(cvt, res_S, nbr, Qw, Kw, TQw, TKw, Vw, cT, sigT,
                                     r_ws, aVe, dXe);
  k4_agg<<<NRES, 128, 0, stream>>>(cvt, res_S, inv_row, r_ws, aVe, dXe, resHn, wt, flag,
                                   resH2, resX2, d_out);
  k6_lig<<<NE1, 256, 0, stream>>>(cvt, res_S, row1, col1, resX2, Qw, Klw, Vw, Vlw, sig1T,
                                  r1w, aVrw, aVlgw);
  k7_finalH<<<NRES, 128, 0, stream>>>(inv_row, res_S, resH2, aVrw, wt, flag, d_out);
  k8_lf2<<<4*LC, 128, 0, stream>>>(col1, r1w, aVlgw, lf, wt, flag, d_out);
}

// Round 7
// 319.689 us; speedup vs baseline: 1.1306x; 1.1306x over previous
//
#include <hip/hip_runtime.h>
#include <hip/hip_bf16.h>
#include <math.h>

typedef __hip_bfloat16 bf16;

#define NRES 256
#define LC   32
#define HCH  128
#define ECH  64
#define NH   4
#define NCA  14
#define KNNK 8
#define DH   32
#define NKE  (NRES*KNNK)      // 2048
#define NEDGE (NKE+NRES)      // 2304
#define NE1  64
#define NROWS (NRES*NCA)      // 3584

// distance tables: nearest-neighbor, h=1/256, domain [0,12]
#define NT     3073
#define TSCALE 256.0f
#define DMAXT  12.0f

// ---- fp32 converted-input region offsets (floats) ----
#define O_RESH   0
#define O_RESX   458752
#define O_LPOS   469504
#define O_LFEAT  469888
#define O_LMASK  486272
#define O_LNG    486400
#define O_LNB    486528
#define O_LN1G   486656
#define O_LN1B   486784
#define O_WQ     486912
#define O_WK     503296
#define O_WV     519680
#define O_WKL    536064
#define O_WVL    552448
#define O_WO     568832
#define O_WOL    585216
#define O_WOL1   601600
#define O_TIW1   617984
#define O_TIB1   658944
#define O_TIW2   659072
#define O_TIB2   659200
#define O_SDW1   659204
#define O_SDB1   667396
#define O_SDW2   667524
#define O_SDB2   668036
#define O_SD1W1  668040
#define O_SD1B1  676232
#define O_SD1W2  676360
#define O_SD1B2  676872
#define TOTCVT   676876
#define CVT_RSV  676880

#define OUTX_OFF 458752
#define OUTL_OFF 469504

__constant__ int c_counts[21] = {14,5,11,8,8,6,9,9,4,10,8,8,9,8,11,7,6,7,14,12,7};

__device__ __forceinline__ float b2f(bf16 x){ return __bfloat162float(x); }
__device__ __forceinline__ float sspf(float x){
  return fmaxf(x,0.f) + log1pf(expf(-fabsf(x))) - 0.6931471805599453f;
}
__device__ __forceinline__ int ccount(int s){ return c_counts[s<0?0:(s>20?20:s)]; }
__device__ __forceinline__ void storeOut(void* out, int isbf, int idx, float v){
  if (isbf) ((bf16*)out)[idx] = __float2bfloat16(v);
  else      ((float*)out)[idx] = v;
}

// ---------------------------------------------------------------- kdet: detect input float dtype
__global__ __launch_bounds__(64) void kdet(const unsigned* __restrict__ resH_raw, int* __restrict__ flag)
{
  int tid = threadIdx.x;
  unsigned w = resH_raw[tid];
  unsigned lo = w & 0xFFFFu;
  int e = (lo >> 7) & 0xFF;
  int good = (lo == 0u) || (e >= 121 && e <= 133);
  unsigned long long m = __ballot(good);
  if (tid == 0) flag[0] = (__popcll(m) >= 40) ? 1 : 0;   // 1 = inputs are bf16
}

// ---------------------------------------------------------------- kcvt: all float inputs -> fp32 copies
__global__ __launch_bounds__(256) void kcvt(
    const int* __restrict__ flag,
    const void* s0,const void* s1,const void* s2,const void* s3,const void* s4,
    const void* s5,const void* s6,const void* s7,const void* s8,const void* s9,
    const void* s10,const void* s11,const void* s12,const void* s13,const void* s14,
    const void* s15,const void* s16,const void* s17,const void* s18,const void* s19,
    const void* s20,const void* s21,const void* s22,const void* s23,const void* s24,
    const void* s25,const void* s26,const void* s27,const void* s28,
    float* __restrict__ dst)
{
  int g = blockIdx.x*256 + threadIdx.x;
  if (g >= TOTCVT) return;
  const void* src; int l;
  if      (g < O_RESX ) { src=s0;  l=g; }
  else if (g < O_LPOS ) { src=s1;  l=g-O_RESX; }
  else if (g < O_LFEAT) { src=s2;  l=g-O_LPOS; }
  else if (g < O_LMASK) { src=s3;  l=g-O_LFEAT; }
  else if (g < O_LNG  ) { src=s4;  l=g-O_LMASK; }
  else if (g < O_LNB  ) { src=s5;  l=g-O_LNG; }
  else if (g < O_LN1G ) { src=s6;  l=g-O_LNB; }
  else if (g < O_LN1B ) { src=s7;  l=g-O_LN1G; }
  else if (g < O_WQ   ) { src=s8;  l=g-O_LN1B; }
  else if (g < O_WK   ) { src=s9;  l=g-O_WQ; }
  else if (g < O_WV   ) { src=s10; l=g-O_WK; }
  else if (g < O_WKL  ) { src=s11; l=g-O_WV; }
  else if (g < O_WVL  ) { src=s12; l=g-O_WKL; }
  else if (g < O_WO   ) { src=s13; l=g-O_WVL; }
  else if (g < O_WOL  ) { src=s14; l=g-O_WO; }
  else if (g < O_WOL1 ) { src=s15; l=g-O_WOL; }
  else if (g < O_TIW1 ) { src=s16; l=g-O_WOL1; }
  else if (g < O_TIB1 ) { src=s17; l=g-O_TIW1; }
  else if (g < O_TIW2 ) { src=s18; l=g-O_TIB1; }
  else if (g < O_TIB2 ) { src=s19; l=g-O_TIW2; }
  else if (g < O_SDW1 ) { src=s20; l=0; }
  else if (g < O_SDB1 ) { src=s21; l=g-O_SDW1; }
  else if (g < O_SDW2 ) { src=s22; l=g-O_SDB1; }
  else if (g < O_SDB2 ) { src=s23; l=g-O_SDW2; }
  else if (g < O_SD1W1) { src=s24; l=g-O_SDB2; }
  else if (g < O_SD1B1) { src=s25; l=g-O_SD1W1; }
  else if (g < O_SD1W2) { src=s26; l=g-O_SD1B1; }
  else if (g < O_SD1B2) { src=s27; l=g-O_SD1W2; }
  else                  { src=s28; l=g-O_SD1B2; }
  float v = (*flag) ? b2f(((const bf16*)src)[l]) : ((const float*)src)[l];
  dst[g] = v;
}

// ---------------------------------------------------------------- ktab: distance-function tables
__global__ __launch_bounds__(128) void ktab(const float* __restrict__ cvt,
    float* __restrict__ cT, float* __restrict__ sigT, float* __restrict__ sig1T)
{
  int i = blockIdx.x, o = threadIdx.x;
  __shared__ float dr[64];
  __shared__ float W[128*65];
  __shared__ float h1[128], h1b[128];
  float d = (float)i * (1.0f/256.0f);
  const float step = 10.0f/63.0f;
  const float coef = -0.5f/(step*step);
  if (o < 64){ float t = d - step*(float)o; dr[o] = expf(coef*t*t); }
  for (int idx=o; idx<8192; idx+=128){ int oo=idx>>6, k=idx&63; W[oo*65+k] = cvt[O_TIW1 + oo*320 + 256 + k]; }
  __syncthreads();
  {
    float c = cvt[O_TIB1+o];
    for (int k=0;k<64;k++) c += dr[k]*W[o*65+k];
    cT[i*128+o] = c;
  }
  __syncthreads();
  for (int idx=o; idx<8192; idx+=128){ int oo=idx>>6, k=idx&63; W[oo*65+k] = cvt[O_SDW1 + idx]; }
  __syncthreads();
  {
    float a = cvt[O_SDB1+o];
    for (int k=0;k<64;k++) a += dr[k]*W[o*65+k];
    h1[o] = fmaxf(a,0.f);
  }
  __syncthreads();
  for (int idx=o; idx<8192; idx+=128){ int oo=idx>>6, k=idx&63; W[oo*65+k] = cvt[O_SD1W1 + idx]; }
  __syncthreads();
  {
    float a2 = cvt[O_SD1B1+o];
    for (int k=0;k<64;k++) a2 += dr[k]*W[o*65+k];
    h1b[o] = fmaxf(a2,0.f);
  }
  __syncthreads();
  if (o < 8){
    int h = o & 3;
    const float* hh = (o<4)? h1 : h1b;
    int wbase = (o<4)? O_SDW2 : O_SD1W2;
    int bbase = (o<4)? O_SDB2 : O_SD1B2;
    float s = cvt[bbase + h];
    for (int k=0;k<128;k++) s += hh[k]*cvt[wbase + h*128 + k];
    if (o<4) sigT[i*4+h] = s; else sig1T[i*4+h] = s;
  }
}

// ---------------------------------------------------------------- k0: transpose weights + inv_row
__global__ __launch_bounds__(256) void k0_prep(
    const float* __restrict__ cvt, const int* __restrict__ row1,
    float* __restrict__ wt, int* __restrict__ inv_row)
{
  int bid = blockIdx.x, tid = threadIdx.x;
  if (bid == 640){
    if (tid < NRES) inv_row[tid] = -1;
    __syncthreads();
    if (tid < NE1) inv_row[row1[tid] & 255] = tid;
    return;
  }
  int gid = bid*256 + tid;
  int m = gid >> 14;
  int j = gid & 16383;
  int o = j >> 7, c = j & 127;
  float v;
  switch(m){
    case 0: v = cvt[O_WQ  + j]; break;
    case 1: v = cvt[O_WK  + j]; break;
    case 2: v = cvt[O_WV  + j]; break;
    case 3: v = cvt[O_WO  + j]; break;
    case 4: v = cvt[O_WKL + j]; break;
    case 5: v = cvt[O_WVL + j]; break;
    case 6: v = cvt[O_WOL + j]; break;
    case 7: v = cvt[O_WOL1+ j]; break;
    case 8: v = cvt[O_TIW1 + o*320 + c]; break;
    default:v = cvt[O_TIW1 + o*320 + 128 + c]; break;
  }
  wt[m*16384 + c*128 + o] = v;
}

// ------------------------------------------------- kProj: LN + {Q,K,V} (+TQ/TK chained) per 16-row tile
__global__ __launch_bounds__(256) void kProj(
    const float* __restrict__ cvt, const float* __restrict__ wt,
    float* __restrict__ resHn, float* __restrict__ Qw, float* __restrict__ Kw,
    float* __restrict__ Vw, float* __restrict__ TQw, float* __restrict__ TKw)
{
  int m = blockIdx.y;
  int rt = blockIdx.x * 16;
  int tid = threadIdx.x;
  __shared__ float Xs[16*129];
  for (int i=tid; i<16*128; i+=256){
    int r=i>>7, c=i&127;
    Xs[r*129+c] = cvt[O_RESH + (rt+r)*HCH + c];
  }
  __syncthreads();
  {
    int wave = tid>>6, lane = tid&63;
    int r = wave*4 + (lane>>4);
    int cb = lane & 15;
    float s=0;
    #pragma unroll
    for (int j=0;j<8;j++) s += Xs[r*129 + cb + 16*j];
    #pragma unroll
    for (int off=1; off<16; off<<=1) s += __shfl_xor(s, off);
    float mu = s*(1.f/HCH);
    float q=0;
    #pragma unroll
    for (int j=0;j<8;j++){ float dv = Xs[r*129+cb+16*j]-mu; q += dv*dv; }
    #pragma unroll
    for (int off=1; off<16; off<<=1) q += __shfl_xor(q, off);
    float inv = rsqrtf(q*(1.f/HCH) + 1e-5f);
    #pragma unroll
    for (int j=0;j<8;j++){
      int c = cb + 16*j;
      float xh = (Xs[r*129+c]-mu)*inv*cvt[O_LNG+c] + cvt[O_LNB+c];
      Xs[r*129+c] = xh;
      if (m==0) resHn[(rt+r)*HCH+c] = xh;
    }
  }
  __syncthreads();
  int tc = (tid & 31) * 4;
  int tr = (tid >> 5) * 2;
  const float* W = wt + m*16384;
  float a00=0,a01=0,a02=0,a03=0, a10=0,a11=0,a12=0,a13=0;
  for (int c=0;c<HCH;c++){
    float4 w4 = *(const float4*)(W + c*128 + tc);
    float x0 = Xs[tr*129 + c];
    float x1 = Xs[(tr+1)*129 + c];
    a00 += x0*w4.x; a01 += x0*w4.y; a02 += x0*w4.z; a03 += x0*w4.w;
    a10 += x1*w4.x; a11 += x1*w4.y; a12 += x1*w4.z; a13 += x1*w4.w;
  }
  float* out = (m==0)? Qw : (m==1)? Kw : Vw;
  *(float4*)(out + (rt+tr  )*HCH + tc) = make_float4(a00,a01,a02,a03);
  *(float4*)(out + (rt+tr+1)*HCH + tc) = make_float4(a10,a11,a12,a13);
  if (m == 2) return;
  __syncthreads();
  Xs[tr*129+tc]=a00; Xs[tr*129+tc+1]=a01; Xs[tr*129+tc+2]=a02; Xs[tr*129+tc+3]=a03;
  Xs[(tr+1)*129+tc]=a10; Xs[(tr+1)*129+tc+1]=a11; Xs[(tr+1)*129+tc+2]=a12; Xs[(tr+1)*129+tc+3]=a13;
  __syncthreads();
  const float* W2 = wt + (8+m)*16384;
  a00=0;a01=0;a02=0;a03=0; a10=0;a11=0;a12=0;a13=0;
  for (int c=0;c<HCH;c++){
    float4 w4 = *(const float4*)(W2 + c*128 + tc);
    float x0 = Xs[tr*129 + c];
    float x1 = Xs[(tr+1)*129 + c];
    a00 += x0*w4.x; a01 += x0*w4.y; a02 += x0*w4.z; a03 += x0*w4.w;
    a10 += x1*w4.x; a11 += x1*w4.y; a12 += x1*w4.z; a13 += x1*w4.w;
  }
  float* out2 = m ? TKw : TQw;
  *(float4*)(out2 + (rt+tr  )*HCH + tc) = make_float4(a00,a01,a02,a03);
  *(float4*)(out2 + (rt+tr+1)*HCH + tc) = make_float4(a10,a11,a12,a13);
}

// ------------------------------------------------- k25: fused KNN (blocks 0..63) + ligand LN/proj (64..127)
__global__ __launch_bounds__(256) void k25_small(
    const float* __restrict__ cvt, const int* __restrict__ batch, const float* __restrict__ wt,
    int* __restrict__ nbr, float* __restrict__ lf, float* __restrict__ Klw, float* __restrict__ Vlw)
{
  int b = blockIdx.x, tid = threadIdx.x;
  if (b < 64){
    // KNN: one wave per residue, shuffle-only
    int wave = tid>>6, lane = tid&63;
    int n = b*4 + wave;
    float cx = cvt[O_RESX+(n*NCA+1)*3+0];
    float cy = cvt[O_RESX+(n*NCA+1)*3+1];
    float cz = cvt[O_RESX+(n*NCA+1)*3+2];
    int bn = batch[n];
    float d2v[4]; int idv[4];
    #pragma unroll
    for (int t=0;t<4;t++){
      int j = lane + 64*t;
      float jx = cvt[O_RESX+(j*NCA+1)*3+0];
      float jy = cvt[O_RESX+(j*NCA+1)*3+1];
      float jz = cvt[O_RESX+(j*NCA+1)*3+2];
      float dx=cx-jx, dy=cy-jy, dz=cz-jz;
      float d2 = dx*dx+dy*dy+dz*dz;
      bool bad = (batch[j]!=bn) || (j==n);
      d2v[t] = bad ? INFINITY : d2;
      idv[t] = j;
    }
    for (int k=0;k<KNNK;k++){
      float dm = d2v[0]; int im = idv[0];
      #pragma unroll
      for (int t=1;t<4;t++)
        if (d2v[t]<dm || (d2v[t]==dm && idv[t]<im)){ dm=d2v[t]; im=idv[t]; }
      #pragma unroll
      for (int off=1; off<64; off<<=1){
        float dn = __shfl_xor(dm, off);
        int   in = __shfl_xor(im, off);
        if (dn<dm || (dn==dm && in<im)){ dm=dn; im=in; }
      }
      if (lane==0) nbr[n*KNNK+k] = im;
      #pragma unroll
      for (int t=0;t<4;t++) if (idv[t]==im) d2v[t] = INFINITY;
    }
    return;
  }
  // ligand LN + Kl/Vl: 2 rows per block
  __shared__ float x2[2][HCH];
  __shared__ float sred2[2][2];
  int row = tid>>7, t = tid&127;
  int rb = (b-64)*2 + row;
  float v = cvt[O_LFEAT + rb*HCH + t];
  float s=v;
  for (int off=1; off<64; off<<=1) s += __shfl_xor(s, off);
  if ((t&63)==0) sred2[row][t>>6]=s;
  __syncthreads();
  float mu=(sred2[row][0]+sred2[row][1])*(1.f/HCH);
  __syncthreads();
  float d=v-mu; s=d*d;
  for (int off=1; off<64; off<<=1) s += __shfl_xor(s, off);
  if ((t&63)==0) sred2[row][t>>6]=s;
  __syncthreads();
  float var=(sred2[row][0]+sred2[row][1])*(1.f/HCH);
  float xh = d*rsqrtf(var+1e-5f)*cvt[O_LN1G+t] + cvt[O_LN1B+t];
  x2[row][t]=xh; lf[rb*HCH+t]=xh;
  __syncthreads();
  const float* WKlt = wt + 4*16384;
  const float* WVlt = wt + 5*16384;
  float aK=0.f, aV=0.f;
  for (int c=0;c<HCH;c++){
    float xc=x2[row][c];
    aK += xc*WKlt[c*128+t];
    aV += xc*WVlt[c*128+t];
  }
  Klw[rb*HCH+t]=aK; Vlw[rb*HCH+t]=aV;
}

// ------------------------------------------------- k3: fused residue-edge, XCD-swizzled, Vc aliases Tq
// blockIdx b: rr = b & 255, slot = b >> 8  -> all 9 edges of residue rr land on XCD (rr % 8)
__global__ __launch_bounds__(256) void k3_edge(
    const float* __restrict__ cvt, const int* __restrict__ res_S, const int* __restrict__ nbr,
    const float* __restrict__ Qw, const float* __restrict__ Kw,
    const float* __restrict__ TQw, const float* __restrict__ TKw,
    const float* __restrict__ Vw, const float* __restrict__ cT, const float* __restrict__ sigT,
    float* __restrict__ r_ws, float* __restrict__ aVe, float* __restrict__ dXe)
{
  __shared__ float Bq[1848], Bk[1848], Tq[1848], Tk[1848];   // stride 132; Vc aliases Tq later
  __shared__ float LG[784], FR[196];
  __shared__ float tw2s[128], tb2s[1], Xr[42], Xc[42], amr[14], amc[14], rpart[56], cnts[2];
  float* Vc = Tq;   // Tq is dead after the logits/fa phase

  int b = blockIdx.x, tid = threadIdx.x;
  int rr = b & 255, slot = b >> 8;
  int e  = (slot < 8) ? (rr*8 + slot) : (2048 + rr);
  int cc = (slot < 8) ? (nbr[rr*8 + slot] & 255) : rr;

  for (int i=tid;i<NCA*HCH;i+=256){
    int p=i>>7, c=i&127;
    Bq[p*132+c]=Qw[rr*1792+i];  Bk[p*132+c]=Kw[cc*1792+i];
    Tq[p*132+c]=TQw[rr*1792+i]; Tk[p*132+c]=TKw[cc*1792+i];
  }
  if (tid < 128) tw2s[tid]=cvt[O_TIW2+tid];
  if (tid == 128) tb2s[0]=cvt[O_TIB2];
  if (tid >= 136 && tid < 178){
    int i=tid-136; int p=i/3, jx=i%3;
    Xr[i] = cvt[O_RESX+(rr*NCA+p)*3+jx];
    Xc[i] = cvt[O_RESX+(cc*NCA+p)*3+jx];
  }
  if (tid >= 242 && tid < 242+NCA){
    int p=tid-242;
    amr[p] = (p < ccount(res_S[rr])) ? 1.f : 0.f;
    amc[p] = (p < ccount(res_S[cc])) ? 1.f : 0.f;
  }
  __syncthreads();

  if (tid < 196){
    int p = tid/14, q = tid%14;
    float dx=Xr[p*3]-Xc[q*3], dy=Xr[p*3+1]-Xc[q*3+1], dz=Xr[p*3+2]-Xc[q*3+2];
    float d = sqrtf(fmaxf(dx*dx+dy*dy+dz*dz, 1e-12f));
    int i0 = (int)(fminf(d, DMAXT)*TSCALE + 0.5f);
    float4 sg = ((const float4*)sigT)[i0];
    const float4* crow = (const float4*)(cT + i0*128);
    float fa = tb2s[0];
    #pragma unroll 8
    for (int j=0;j<32;j++){
      float4 cb = crow[j];
      int o = 4*j;
      fa += fmaxf(Tq[p*132+o  ]+Tk[q*132+o  ]+cb.x, 0.f)*tw2s[o  ];
      fa += fmaxf(Tq[p*132+o+1]+Tk[q*132+o+1]+cb.y, 0.f)*tw2s[o+1];
      fa += fmaxf(Tq[p*132+o+2]+Tk[q*132+o+2]+cb.z, 0.f)*tw2s[o+2];
      fa += fmaxf(Tq[p*132+o+3]+Tk[q*132+o+3]+cb.w, 0.f)*tw2s[o+3];
    }
    float qk0=0,qk1=0,qk2=0,qk3=0;
    #pragma unroll
    for (int dd=0;dd<DH;dd++){
      qk0 += Bq[p*132+dd]   *Bk[q*132+dd];
      qk1 += Bq[p*132+32+dd]*Bk[q*132+32+dd];
      qk2 += Bq[p*132+64+dd]*Bk[q*132+64+dd];
      qk3 += Bq[p*132+96+dd]*Bk[q*132+96+dd];
    }
    const float isq = 0.17677669529663687f;
    LG[0*196+tid] = qk0*isq + sg.x;
    LG[1*196+tid] = qk1*isq + sg.y;
    LG[2*196+tid] = qk2*isq + sg.z;
    LG[3*196+tid] = qk3*isq + sg.w;
    FR[tid] = fa;
  }
  __syncthreads();   // Tq dead beyond this point; Vc (alias) staged next

  for (int i=tid;i<NCA*HCH;i+=256){
    int p=i>>7, c=i&127;
    Vc[p*132+c]=Vw[cc*1792+i];
  }
  if (tid < 56){
    int h=tid/14, pp=tid%14;
    float ap = amr[pp];
    float row[NCA];
    float s=0;
    #pragma unroll
    for (int qq=0;qq<NCA;qq++){ row[qq]=LG[h*196+pp*14+qq]; s += row[qq]*amc[qq]; }
    rpart[h*14+pp] = s*ap;
    float m=-INFINITY;
    #pragma unroll
    for (int qq=0;qq<NCA;qq++) m=fmaxf(m,row[qq]);
    float sum=0;
    #pragma unroll
    for (int qq=0;qq<NCA;qq++){ row[qq]=expf(row[qq]-m); sum+=row[qq]; }
    float inv=1.f/sum, s2=0;
    #pragma unroll
    for (int qq=0;qq<NCA;qq++){ row[qq]=row[qq]*inv*ap*amc[qq]; s2+=row[qq]; }
    float inv2=1.f/(s2+1e-7f);
    #pragma unroll
    for (int qq=0;qq<NCA;qq++) LG[h*196+pp*14+qq]=row[qq]*inv2;
  }
  if (tid == 56){
    float sr=0, sc=0;
    for (int i=0;i<NCA;i++){ sr+=amr[i]; sc+=amc[i]; }
    cnts[0]=sr; cnts[1]=sc;
  }
  __syncthreads();
  if (tid < NH){
    float s=0;
    for (int pp=0;pp<NCA;pp++) s += rpart[tid*14+pp];
    r_ws[e*NH+tid] = s/(cnts[0]*cnts[1]);
  }
  if (tid < 196){
    int p=tid/14, q=tid%14;
    float ma = 0.25f*(LG[p*14+q] + LG[196+p*14+q] + LG[392+p*14+q] + LG[588+p*14+q]);
    FR[tid] *= ma;
  }
  __syncthreads();
  if (tid < NCA){
    int pp=tid;
    float ax=0, ay=0, az=0;
    #pragma unroll
    for (int qq=0;qq<NCA;qq++){
      float dx=Xr[pp*3]-Xc[qq*3], dy=Xr[pp*3+1]-Xc[qq*3+1], dz=Xr[pp*3+2]-Xc[qq*3+2];
      float nrm = sqrtf(fmaxf(dx*dx+dy*dy+dz*dz,1e-12f));
      float sc = FR[pp*14+qq]/(nrm+1e-5f);
      ax += sc*dx; ay += sc*dy; az += sc*dz;
    }
    dXe[(e*NCA+pp)*3+0]=ax; dXe[(e*NCA+pp)*3+1]=ay; dXe[(e*NCA+pp)*3+2]=az;
  }
  #pragma unroll
  for (int rep=0;rep<7;rep++){
    int jdx = rep*256 + tid;
    int h = jdx/448, rem = jdx%448;
    int pp = rem>>5, dd = rem&31;
    float acc=0;
    #pragma unroll
    for (int qq=0;qq<NCA;qq++) acc += LG[h*196+pp*14+qq]*Vc[qq*132 + h*32 + dd];
    aVe[e*1792 + jdx] = acc;
  }
}

// ------------------------------------------------- k4: per-residue beta + updH + WO + dX
__global__ __launch_bounds__(128) void k4_agg(
    const float* __restrict__ cvt, const int* __restrict__ res_S, const int* __restrict__ inv_row,
    const float* __restrict__ r_ws, const float* __restrict__ aVe, const float* __restrict__ dXe,
    const float* __restrict__ resHn, const float* __restrict__ wt, const int* __restrict__ flag,
    float* __restrict__ resH2, float* __restrict__ resX2, void* __restrict__ d_out)
{
  int n = blockIdx.x, tid = threadIdx.x;
  __shared__ float beta[9][NH];
  __shared__ float betam[9];
  __shared__ float Xs[NCA][HCH];
  if (tid < NH){
    int h = tid;
    float rv[9], m=-INFINITY;
    #pragma unroll
    for (int k=0;k<9;k++){
      int ek = (k<KNNK)? n*KNNK+k : NKE+n;
      rv[k] = r_ws[ek*NH+h];
      m = fmaxf(m, rv[k]);
    }
    float s=0;
    #pragma unroll
    for (int k=0;k<9;k++){ rv[k]=expf(rv[k]-m); s+=rv[k]; }
    #pragma unroll
    for (int k=0;k<9;k++) beta[k][h]=rv[k]/s;
  }
  __syncthreads();
  if (tid < 9) betam[tid] = 0.25f*(beta[tid][0]+beta[tid][1]+beta[tid][2]+beta[tid][3]);
  int h = tid>>5, dd = tid&31;
  float bh[9];
  #pragma unroll
  for (int k=0;k<9;k++) bh[k]=beta[k][h];
  for (int p=0;p<NCA;p++){
    float u=0;
    #pragma unroll
    for (int k=0;k<9;k++){
      int ek = (k<KNNK)? n*KNNK+k : NKE+n;
      u += bh[k]*aVe[ek*1792 + h*448 + p*32 + dd];
    }
    Xs[p][tid] = sspf(u);
  }
  __syncthreads();
  const float* WOt = wt + 3*16384;
  float acc[NCA];
  #pragma unroll
  for (int p=0;p<NCA;p++) acc[p]=0.f;
  for (int c=0;c<HCH;c++){
    float w = WOt[c*128+tid];
    #pragma unroll
    for (int p=0;p<NCA;p++) acc[p] += Xs[p][c]*w;
  }
  int cnt = ccount(res_S[n]);
  for (int p=0;p<NCA;p++){
    float am = (p<cnt)?1.f:0.f;
    float outv = (resHn[(n*NCA+p)*HCH+tid] + acc[p])*am;
    resH2[(n*NCA+p)*HCH+tid] = outv;
  }
  if (tid < NCA*3){
    int isbf = *flag;
    int p=tid/3, jx=tid%3;
    float s=0;
    #pragma unroll
    for (int k=0;k<9;k++){
      int ek=(k<KNNK)? n*KNNK+k : NKE+n;
      s += betam[k]*dXe[(ek*NCA+p)*3+jx];
    }
    float base = cvt[O_RESX+(n*NCA+p)*3+jx];
    float v = (inv_row[n]>=0) ? base + fminf(fmaxf(s,-3.f),3.f) : base;
    resX2[(n*NCA+p)*3+jx] = v;
    storeOut(d_out, isbf, OUTX_OFF + (n*NCA+p)*3+jx, v);
  }
}

// ------------------------------------------------- k6: fused ligand-edge (logits + softmaxes + aVr/aVlg)
__global__ __launch_bounds__(256) void k6_lig(
    const float* __restrict__ cvt, const int* __restrict__ res_S,
    const int* __restrict__ row1, const int* __restrict__ col1,
    const float* __restrict__ resX2, const float* __restrict__ Qw, const float* __restrict__ Klw,
    const float* __restrict__ Vw, const float* __restrict__ Vlw, const float* __restrict__ sig1T,
    float* __restrict__ r1_ws, float* __restrict__ aVr, float* __restrict__ aVlg)
{
  __shared__ __align__(16) float S[10042];
  float* Bq  = S;
  float* Bk  = S + 1848;
  float* LG  = S;
  float* Vl  = S + 1848;
  float* ALs = S + 6104;
  float* Vr  = S + 7896;
  float* EX  = S + 9744;
  float* Xr = EX;
  float* Lp = EX + 42;
  float* amr = EX + 138;
  float* lm  = EX + 152;
  float* s2r = EX + 184;
  float* rpart = EX + 240;
  float* cnts  = EX + 296;
  int e = blockIdx.x, tid = threadIdx.x;
  int rr = row1[e] & 255, cb = col1[e] & 3;

  for (int i=tid;i<NCA*HCH;i+=256){ int p=i>>7,c=i&127; Bq[p*132+c]=Qw[rr*1792+i]; Vr[p*132+c]=Vw[rr*1792+i]; }
  for (int i=tid;i<LC*HCH;i+=256){ int q=i>>7,c=i&127; Bk[q*133+c]=Klw[cb*LC*HCH+i]; }
  if (tid >= 8 && tid < 50){ int i=tid-8; int p=i/3,jx=i%3; Xr[i]=resX2[(rr*NCA+p)*3+jx]; }
  if (tid >= 64 && tid < 160){ int i=tid-64; int q=i/3,jx=i%3; Lp[i]=cvt[O_LPOS+(cb*LC+q)*3+jx]; }
  if (tid >= 160 && tid < 160+NCA) amr[tid-160]=((tid-160) < ccount(res_S[rr]))?1.f:0.f;
  if (tid >= 192 && tid < 224) lm[tid-192]=cvt[O_LMASK + cb*LC + tid-192];
  __syncthreads();

  float l0[2][4];
  int npair = (tid < 192) ? 2 : 1;
  for (int w=0; w<npair; w++){
    int pair = tid + w*256;
    int p = pair>>5, q = pair&31;
    float dx=Xr[p*3]-Lp[q*3], dy=Xr[p*3+1]-Lp[q*3+1], dz=Xr[p*3+2]-Lp[q*3+2];
    float d = sqrtf(fmaxf(dx*dx+dy*dy+dz*dz,1e-12f));
    int i0 = (int)(fminf(d, DMAXT)*TSCALE + 0.5f);
    float4 sg = ((const float4*)sig1T)[i0];
    float q0=0,q1=0,q2=0,q3=0;
    #pragma unroll
    for (int dd=0;dd<DH;dd++){
      q0 += Bq[p*132+dd]   *Bk[q*133+dd];
      q1 += Bq[p*132+32+dd]*Bk[q*133+32+dd];
      q2 += Bq[p*132+64+dd]*Bk[q*133+64+dd];
      q3 += Bq[p*132+96+dd]*Bk[q*133+96+dd];
    }
    const float isq=0.17677669529663687f;
    l0[w][0]=q0*isq+sg.x; l0[w][1]=q1*isq+sg.y; l0[w][2]=q2*isq+sg.z; l0[w][3]=q3*isq+sg.w;
  }
  __syncthreads();
  for (int w=0; w<npair; w++){
    int pair = tid + w*256;
    LG[0*448+pair]=l0[w][0]; LG[1*448+pair]=l0[w][1]; LG[2*448+pair]=l0[w][2]; LG[3*448+pair]=l0[w][3];
  }
  for (int i=tid;i<LC*HCH;i+=256){ int q=i>>7,c=i&127; Vl[q*132+c]=Vlw[cb*LC*HCH+i]; }
  __syncthreads();

  if (tid < 56){
    int h=tid/14, pp=tid%14;
    float ap=amr[pp];
    float s=0, m=-INFINITY;
    for (int qq=0;qq<LC;qq++){ float v=LG[h*448+pp*32+qq]; s+=v*lm[qq]; m=fmaxf(m,v); }
    rpart[h*14+pp]=s*ap;
    float sum=0;
    for (int qq=0;qq<LC;qq++) sum+=expf(LG[h*448+pp*32+qq]-m);
    float inv=1.f/sum, s2=0;
    for (int qq=0;qq<LC;qq++) s2 += expf(LG[h*448+pp*32+qq]-m)*inv*ap*lm[qq];
    s2r[h*14+pp] = s2/(s2+1e-7f);
  }
  if (tid==56){
    float sr=0,sl=0;
    for(int i=0;i<NCA;i++) sr+=amr[i];
    for(int i=0;i<LC;i++) sl+=lm[i];
    cnts[0]=sr; cnts[1]=sl;
  }
  __syncthreads();
  if (tid < NH){
    float s=0; for (int pp=0;pp<NCA;pp++) s+=rpart[tid*14+pp];
    r1_ws[e*NH+tid]=s/(cnts[0]*cnts[1]);
  }
  if (tid < NH*LC){
    int h=tid>>5, qq=tid&31;
    float m=-INFINITY;
    for (int pp=0;pp<NCA;pp++) m=fmaxf(m,LG[h*448+pp*32+qq]);
    float sum=0;
    for (int pp=0;pp<NCA;pp++) sum+=expf(LG[h*448+pp*32+qq]-m);
    float inv=1.f/sum;
    float lq=lm[qq];
    for (int pp=0;pp<NCA;pp++){
      float a=expf(LG[h*448+pp*32+qq]-m)*inv*amr[pp]*lq;
      ALs[h*448+pp*32+qq]=a/(s2r[h*14+pp]+1e-7f);
    }
  }
  __syncthreads();
  if (tid < 56){
    int h=tid/14, pp=tid%14;
    float ap=amr[pp];
    float m=-INFINITY;
    for (int qq=0;qq<LC;qq++) m=fmaxf(m,LG[h*448+pp*32+qq]);
    float row[LC];
    float sum=0;
    for (int qq=0;qq<LC;qq++){ row[qq]=expf(LG[h*448+pp*32+qq]-m); sum+=row[qq]; }
    float inv=1.f/sum, s2=0;
    for (int qq=0;qq<LC;qq++){ row[qq]=row[qq]*inv*ap*lm[qq]; s2+=row[qq]; }
    float inv2=1.f/(s2+1e-7f);
    for (int qq=0;qq<LC;qq++) LG[h*448+pp*32+qq]=row[qq]*inv2;
  }
  __syncthreads();
  for (int j=tid;j<NH*NCA*DH;j+=256){
    int h=j/448, rem=j%448, pp=rem>>5, dd=rem&31;
    float acc=0;
    #pragma unroll
    for (int qq=0;qq<LC;qq++) acc += LG[h*448+pp*32+qq]*Vl[qq*132+h*32+dd];
    aVr[e*1792+j]=acc;
  }
  for (int j=tid;j<NH*LC*DH;j+=256){
    int h=j>>10, rem=j&1023, qq=rem>>5, dd=rem&31;
    float acc=0;
    #pragma unroll
    for (int pp=0;pp<NCA;pp++) acc += ALs[h*448+pp*32+qq]*Vr[pp*132+h*32+dd];
    aVlg[e*4096+j]=acc;
  }
}

// ------------------------------------------------- k78: finalize res_H3 (blocks 0..255) + lf2 (256..383)
__global__ __launch_bounds__(128) void k78_final(
    const int* __restrict__ inv_row, const int* __restrict__ res_S, const int* __restrict__ col1,
    const float* __restrict__ resH2, const float* __restrict__ aVr,
    const float* __restrict__ r1_ws, const float* __restrict__ aVlg, const float* __restrict__ lf,
    const float* __restrict__ wt, const int* __restrict__ flag, void* __restrict__ d_out)
{
  int bb = blockIdx.x, tid = threadIdx.x;
  if (bb < 256){
    int n = bb;
    int e = inv_row[n];
    __shared__ float G[NCA][HCH];
    if (e>=0){
      for (int j=tid;j<NCA*HCH;j+=128){
        int h=j/448, rem=j%448, pp=rem>>5, dd=rem&31;
        G[pp][h*DH+dd] = sspf(aVr[e*1792+j]);
      }
    }
    __syncthreads();
    float acc[NCA];
    #pragma unroll
    for (int p=0;p<NCA;p++) acc[p]=0.f;
    if (e>=0){
      const float* WOlt = wt + 6*16384;
      for (int c=0;c<HCH;c++){
        float w=WOlt[c*128+tid];
        #pragma unroll
        for (int p=0;p<NCA;p++) acc[p]+=G[p][c]*w;
      }
    }
    int cnt=ccount(res_S[n]);
    int isbf = *flag;
    for (int p=0;p<NCA;p++){
      float am=(p<cnt)?1.f:0.f;
      float v=(resH2[(n*NCA+p)*HCH+tid]+acc[p])*am;
      storeOut(d_out, isbf, (n*NCA+p)*HCH+tid, v);
    }
    return;
  }
  // lf2 path
  int rb = bb - 256;
  int b = rb>>5, q = rb&31;
  __shared__ float bw[NE1][NH];
  __shared__ float xs[HCH];
  if (tid<NH){
    int h=tid;
    float m=-INFINITY;
    for (int e=0;e<NE1;e++) if ((col1[e]&3)==b) m=fmaxf(m, r1_ws[e*NH+h]);
    float s=0;
    for (int e=0;e<NE1;e++) if ((col1[e]&3)==b) s+=expf(r1_ws[e*NH+h]-m);
    for (int e=0;e<NE1;e++) bw[e][h] = ((col1[e]&3)==b)? expf(r1_ws[e*NH+h]-m)/s : 0.f;
  }
  __syncthreads();
  int h=tid>>5, dd=tid&31;
  float u=0;
  for (int e=0;e<NE1;e++) u += bw[e][h]*aVlg[e*4096 + h*1024 + q*32 + dd];
  xs[tid]=sspf(u);
  __syncthreads();
  const float* WOl1t = wt + 7*16384;
  float acc=0;
  for (int c=0;c<HCH;c++) acc += xs[c]*WOl1t[c*128+tid];
  float v = lf[rb*HCH+tid] + acc;
  storeOut(d_out, *flag, OUTL_OFF + rb*HCH+tid, v);
}

// ================================================================ launch
extern "C" void kernel_launch(void* const* d_in, const int* in_sizes, int n_in,
                              void* d_out, int out_size, void* d_ws, size_t ws_size,
                              hipStream_t stream)
{
  const int* res_S = (const int*)d_in[29];
  const int* batch = (const int*)d_in[30];
  const int* row1  = (const int*)d_in[32];
  const int* col1  = (const int*)d_in[33];

  float* wsf = (float*)d_ws;
  size_t o = 0;
  int*   flag    = (int*)(wsf + o); o += 4;
  float* cvt     = wsf + o; o += CVT_RSV;
  float* wt      = wsf + o; o += 10*16384;
  int*   inv_row = (int*)(wsf + o); o += 256;
  int*   nbr     = (int*)(wsf + o); o += NRES*KNNK;
  float* resHn   = wsf + o; o += NROWS*HCH;
  float* Qw      = wsf + o; o += NROWS*HCH;
  float* Kw      = wsf + o; o += NROWS*HCH;
  float* Vw      = wsf + o; o += NROWS*HCH;
  float* TQw     = wsf + o; o += NROWS*HCH;
  float* TKw     = wsf + o; o += NROWS*HCH;
  float* r_ws    = wsf + o; o += NEDGE*NH;
  float* aVe     = wsf + o; o += (size_t)NEDGE*1792;
  float* dXe     = wsf + o; o += NEDGE*NCA*3;
  float* resH2   = wsf + o; o += NROWS*HCH;
  float* resX2   = wsf + o; o += NRES*NCA*3;
  float* lf      = wsf + o; o += 4*LC*HCH;
  float* Klw     = wsf + o; o += 4*LC*HCH;
  float* Vlw     = wsf + o; o += 4*LC*HCH;
  float* r1w     = wsf + o; o += NE1*NH;
  float* aVrw    = wsf + o; o += NE1*1792;
  float* aVlgw   = wsf + o; o += NE1*4096;
  float* cT      = wsf + o; o += (size_t)NT*128;
  float* sigT    = wsf + o; o += NT*4;
  float* sig1T   = wsf + o; o += NT*4;

  kdet<<<1, 64, 0, stream>>>((const unsigned*)d_in[0], flag);
  kcvt<<<(TOTCVT+255)/256, 256, 0, stream>>>(flag,
      d_in[0],d_in[1],d_in[2],d_in[3],d_in[4],d_in[5],d_in[6],d_in[7],d_in[8],
      d_in[9],d_in[10],d_in[11],d_in[12],d_in[13],d_in[14],d_in[15],d_in[16],
      d_in[17],d_in[18],d_in[19],d_in[20],d_in[21],d_in[22],d_in[23],d_in[24],
      d_in[25],d_in[26],d_in[27],d_in[28], cvt);
  ktab<<<NT, 128, 0, stream>>>(cvt, cT, sigT, sig1T);
  k0_prep<<<641, 256, 0, stream>>>(cvt, row1, wt, inv_row);
  kProj<<<dim3(NROWS/16, 3), 256, 0, stream>>>(cvt, wt, resHn, Qw, Kw, Vw, TQw, TKw);
  k25_small<<<128, 256, 0, stream>>>(cvt, batch, wt, nbr, lf, Klw, Vlw);
  k3_edge<<<NEDGE, 256, 0, stream>>>(cvt, res_S, nbr, Qw, Kw, TQw, TKw, Vw, cT, sigT,
                                     r_ws, aVe, dXe);
  k4_agg<<<NRES, 128, 0, stream>>>(cvt, res_S, inv_row, r_ws, aVe, dXe, resHn, wt, flag,
                                   resH2, resX2, d_out);
  k6_lig<<<NE1, 256, 0, stream>>>(cvt, res_S, row1, col1, resX2, Qw, Klw, Vw, Vlw, sig1T,
                                  r1w, aVrw, aVlgw);
  k78_final<<<384, 128, 0, stream>>>(inv_row, res_S, col1, resH2, aVrw, r1w, aVlgw, lf,
                                     wt, flag, d_out);
}

// Round 8
// 312.772 us; speedup vs baseline: 1.1556x; 1.0221x over previous
//
#include <hip/hip_runtime.h>
#include <hip/hip_bf16.h>
#include <math.h>

typedef __hip_bfloat16 bf16;

#define NRES 256
#define LC   32
#define HCH  128
#define ECH  64
#define NH   4
#define NCA  14
#define KNNK 8
#define DH   32
#define NKE  (NRES*KNNK)      // 2048
#define NEDGE (NKE+NRES)      // 2304
#define NE1  64
#define NROWS (NRES*NCA)      // 3584

// distance tables: nearest-neighbor, h=1/256, domain [0,12]
#define NT     3073
#define TSCALE 256.0f
#define DMAXT  12.0f

// ---- fp32 converted-input region offsets (floats) ----
#define O_RESH   0
#define O_RESX   458752
#define O_LPOS   469504
#define O_LFEAT  469888
#define O_LMASK  486272
#define O_LNG    486400
#define O_LNB    486528
#define O_LN1G   486656
#define O_LN1B   486784
#define O_WQ     486912
#define O_WK     503296
#define O_WV     519680
#define O_WKL    536064
#define O_WVL    552448
#define O_WO     568832
#define O_WOL    585216
#define O_WOL1   601600
#define O_TIW1   617984
#define O_TIB1   658944
#define O_TIW2   659072
#define O_TIB2   659200
#define O_SDW1   659204
#define O_SDB1   667396
#define O_SDW2   667524
#define O_SDB2   668036
#define O_SD1W1  668040
#define O_SD1B1  676232
#define O_SD1W2  676360
#define O_SD1B2  676872
#define TOTCVT   676876
#define CVT_RSV  676880

#define OUTX_OFF 458752
#define OUTL_OFF 469504

__constant__ int c_counts[21] = {14,5,11,8,8,6,9,9,4,10,8,8,9,8,11,7,6,7,14,12,7};

__device__ __forceinline__ float b2f(bf16 x){ return __bfloat162float(x); }
__device__ __forceinline__ float sspf(float x){
  return fmaxf(x,0.f) + log1pf(expf(-fabsf(x))) - 0.6931471805599453f;
}
__device__ __forceinline__ float bflo(unsigned u){ return __uint_as_float(u<<16); }          // element 2k (low half)
__device__ __forceinline__ float bfhi(unsigned u){ return __uint_as_float(u & 0xffff0000u); } // element 2k+1
__device__ __forceinline__ unsigned short f2bs(float v){ bf16 b=__float2bfloat16(v); return *(unsigned short*)&b; }
__device__ __forceinline__ unsigned pack2(float a, float b){
  return (unsigned)f2bs(a) | ((unsigned)f2bs(b)<<16);
}
__device__ __forceinline__ int ccount(int s){ return c_counts[s<0?0:(s>20?20:s)]; }
__device__ __forceinline__ void storeOut(void* out, int isbf, int idx, float v){
  if (isbf) ((bf16*)out)[idx] = __float2bfloat16(v);
  else      ((float*)out)[idx] = v;
}

// ---------------------------------------------------------------- kdet: detect input float dtype
__global__ __launch_bounds__(64) void kdet(const unsigned* __restrict__ resH_raw, int* __restrict__ flag)
{
  int tid = threadIdx.x;
  unsigned w = resH_raw[tid];
  unsigned lo = w & 0xFFFFu;
  int e = (lo >> 7) & 0xFF;
  int good = (lo == 0u) || (e >= 121 && e <= 133);
  unsigned long long m = __ballot(good);
  if (tid == 0) flag[0] = (__popcll(m) >= 40) ? 1 : 0;   // 1 = inputs are bf16
}

// ---------------------------------------------------------------- kcvt: all float inputs -> fp32 copies
__global__ __launch_bounds__(256) void kcvt(
    const int* __restrict__ flag,
    const void* s0,const void* s1,const void* s2,const void* s3,const void* s4,
    const void* s5,const void* s6,const void* s7,const void* s8,const void* s9,
    const void* s10,const void* s11,const void* s12,const void* s13,const void* s14,
    const void* s15,const void* s16,const void* s17,const void* s18,const void* s19,
    const void* s20,const void* s21,const void* s22,const void* s23,const void* s24,
    const void* s25,const void* s26,const void* s27,const void* s28,
    float* __restrict__ dst)
{
  int g = blockIdx.x*256 + threadIdx.x;
  if (g >= TOTCVT) return;
  const void* src; int l;
  if      (g < O_RESX ) { src=s0;  l=g; }
  else if (g < O_LPOS ) { src=s1;  l=g-O_RESX; }
  else if (g < O_LFEAT) { src=s2;  l=g-O_LPOS; }
  else if (g < O_LMASK) { src=s3;  l=g-O_LFEAT; }
  else if (g < O_LNG  ) { src=s4;  l=g-O_LMASK; }
  else if (g < O_LNB  ) { src=s5;  l=g-O_LNG; }
  else if (g < O_LN1G ) { src=s6;  l=g-O_LNB; }
  else if (g < O_LN1B ) { src=s7;  l=g-O_LN1G; }
  else if (g < O_WQ   ) { src=s8;  l=g-O_LN1B; }
  else if (g < O_WK   ) { src=s9;  l=g-O_WQ; }
  else if (g < O_WV   ) { src=s10; l=g-O_WK; }
  else if (g < O_WKL  ) { src=s11; l=g-O_WV; }
  else if (g < O_WVL  ) { src=s12; l=g-O_WKL; }
  else if (g < O_WO   ) { src=s13; l=g-O_WVL; }
  else if (g < O_WOL  ) { src=s14; l=g-O_WO; }
  else if (g < O_WOL1 ) { src=s15; l=g-O_WOL; }
  else if (g < O_TIW1 ) { src=s16; l=g-O_WOL1; }
  else if (g < O_TIB1 ) { src=s17; l=g-O_TIW1; }
  else if (g < O_TIW2 ) { src=s18; l=g-O_TIB1; }
  else if (g < O_TIB2 ) { src=s19; l=g-O_TIW2; }
  else if (g < O_SDW1 ) { src=s20; l=0; }
  else if (g < O_SDB1 ) { src=s21; l=g-O_SDW1; }
  else if (g < O_SDW2 ) { src=s22; l=g-O_SDB1; }
  else if (g < O_SDB2 ) { src=s23; l=g-O_SDW2; }
  else if (g < O_SD1W1) { src=s24; l=g-O_SDB2; }
  else if (g < O_SD1B1) { src=s25; l=g-O_SD1W1; }
  else if (g < O_SD1W2) { src=s26; l=g-O_SD1B1; }
  else if (g < O_SD1B2) { src=s27; l=g-O_SD1W2; }
  else                  { src=s28; l=g-O_SD1B2; }
  float v = (*flag) ? b2f(((const bf16*)src)[l]) : ((const float*)src)[l];
  dst[g] = v;
}

// ---------------------------------------------------------------- ktab: distance-function tables
__global__ __launch_bounds__(128) void ktab(const float* __restrict__ cvt,
    float* __restrict__ cT, float* __restrict__ sigT, float* __restrict__ sig1T)
{
  int i = blockIdx.x, o = threadIdx.x;
  __shared__ float dr[64];
  __shared__ float W[128*65];
  __shared__ float h1[128], h1b[128];
  float d = (float)i * (1.0f/256.0f);
  const float step = 10.0f/63.0f;
  const float coef = -0.5f/(step*step);
  if (o < 64){ float t = d - step*(float)o; dr[o] = expf(coef*t*t); }
  for (int idx=o; idx<8192; idx+=128){ int oo=idx>>6, k=idx&63; W[oo*65+k] = cvt[O_TIW1 + oo*320 + 256 + k]; }
  __syncthreads();
  {
    float c = cvt[O_TIB1+o];
    for (int k=0;k<64;k++) c += dr[k]*W[o*65+k];
    cT[i*128+o] = c;
  }
  __syncthreads();
  for (int idx=o; idx<8192; idx+=128){ int oo=idx>>6, k=idx&63; W[oo*65+k] = cvt[O_SDW1 + idx]; }
  __syncthreads();
  {
    float a = cvt[O_SDB1+o];
    for (int k=0;k<64;k++) a += dr[k]*W[o*65+k];
    h1[o] = fmaxf(a,0.f);
  }
  __syncthreads();
  for (int idx=o; idx<8192; idx+=128){ int oo=idx>>6, k=idx&63; W[oo*65+k] = cvt[O_SD1W1 + idx]; }
  __syncthreads();
  {
    float a2 = cvt[O_SD1B1+o];
    for (int k=0;k<64;k++) a2 += dr[k]*W[o*65+k];
    h1b[o] = fmaxf(a2,0.f);
  }
  __syncthreads();
  if (o < 8){
    int h = o & 3;
    const float* hh = (o<4)? h1 : h1b;
    int wbase = (o<4)? O_SDW2 : O_SD1W2;
    int bbase = (o<4)? O_SDB2 : O_SD1B2;
    float s = cvt[bbase + h];
    for (int k=0;k<128;k++) s += hh[k]*cvt[wbase + h*128 + k];
    if (o<4) sigT[i*4+h] = s; else sig1T[i*4+h] = s;
  }
}

// ---------------------------------------------------------------- k0: transpose weights + inv_row
__global__ __launch_bounds__(256) void k0_prep(
    const float* __restrict__ cvt, const int* __restrict__ row1,
    float* __restrict__ wt, int* __restrict__ inv_row)
{
  int bid = blockIdx.x, tid = threadIdx.x;
  if (bid == 640){
    if (tid < NRES) inv_row[tid] = -1;
    __syncthreads();
    if (tid < NE1) inv_row[row1[tid] & 255] = tid;
    return;
  }
  int gid = bid*256 + tid;
  int m = gid >> 14;
  int j = gid & 16383;
  int o = j >> 7, c = j & 127;
  float v;
  switch(m){
    case 0: v = cvt[O_WQ  + j]; break;
    case 1: v = cvt[O_WK  + j]; break;
    case 2: v = cvt[O_WV  + j]; break;
    case 3: v = cvt[O_WO  + j]; break;
    case 4: v = cvt[O_WKL + j]; break;
    case 5: v = cvt[O_WVL + j]; break;
    case 6: v = cvt[O_WOL + j]; break;
    case 7: v = cvt[O_WOL1+ j]; break;
    case 8: v = cvt[O_TIW1 + o*320 + c]; break;
    default:v = cvt[O_TIW1 + o*320 + 128 + c]; break;
  }
  wt[m*16384 + c*128 + o] = v;
}

// ------------------------------------------------- kProj: LN + {Q,K,V} (+TQ/TK chained); bf16 outputs
__global__ __launch_bounds__(256) void kProj(
    const float* __restrict__ cvt, const float* __restrict__ wt,
    float* __restrict__ resHn, bf16* __restrict__ Qw16, bf16* __restrict__ Kw16,
    bf16* __restrict__ Vw16, bf16* __restrict__ TQw16, bf16* __restrict__ TKw16)
{
  int m = blockIdx.y;
  int rt = blockIdx.x * 16;
  int tid = threadIdx.x;
  __shared__ float Xs[16*129];
  for (int i=tid; i<16*128; i+=256){
    int r=i>>7, c=i&127;
    Xs[r*129+c] = cvt[O_RESH + (rt+r)*HCH + c];
  }
  __syncthreads();
  {
    int wave = tid>>6, lane = tid&63;
    int r = wave*4 + (lane>>4);
    int cb = lane & 15;
    float s=0;
    #pragma unroll
    for (int j=0;j<8;j++) s += Xs[r*129 + cb + 16*j];
    #pragma unroll
    for (int off=1; off<16; off<<=1) s += __shfl_xor(s, off);
    float mu = s*(1.f/HCH);
    float q=0;
    #pragma unroll
    for (int j=0;j<8;j++){ float dv = Xs[r*129+cb+16*j]-mu; q += dv*dv; }
    #pragma unroll
    for (int off=1; off<16; off<<=1) q += __shfl_xor(q, off);
    float inv = rsqrtf(q*(1.f/HCH) + 1e-5f);
    #pragma unroll
    for (int j=0;j<8;j++){
      int c = cb + 16*j;
      float xh = (Xs[r*129+c]-mu)*inv*cvt[O_LNG+c] + cvt[O_LNB+c];
      Xs[r*129+c] = xh;
      if (m==0) resHn[(rt+r)*HCH+c] = xh;
    }
  }
  __syncthreads();
  int tc = (tid & 31) * 4;
  int tr = (tid >> 5) * 2;
  const float* W = wt + m*16384;
  float a00=0,a01=0,a02=0,a03=0, a10=0,a11=0,a12=0,a13=0;
  for (int c=0;c<HCH;c++){
    float4 w4 = *(const float4*)(W + c*128 + tc);
    float x0 = Xs[tr*129 + c];
    float x1 = Xs[(tr+1)*129 + c];
    a00 += x0*w4.x; a01 += x0*w4.y; a02 += x0*w4.z; a03 += x0*w4.w;
    a10 += x1*w4.x; a11 += x1*w4.y; a12 += x1*w4.z; a13 += x1*w4.w;
  }
  bf16* out = (m==0)? Qw16 : (m==1)? Kw16 : Vw16;
  {
    unsigned* o0 = (unsigned*)(out + (rt+tr  )*HCH + tc);
    unsigned* o1 = (unsigned*)(out + (rt+tr+1)*HCH + tc);
    o0[0]=pack2(a00,a01); o0[1]=pack2(a02,a03);
    o1[0]=pack2(a10,a11); o1[1]=pack2(a12,a13);
  }
  if (m == 2) return;
  __syncthreads();
  Xs[tr*129+tc]=a00; Xs[tr*129+tc+1]=a01; Xs[tr*129+tc+2]=a02; Xs[tr*129+tc+3]=a03;
  Xs[(tr+1)*129+tc]=a10; Xs[(tr+1)*129+tc+1]=a11; Xs[(tr+1)*129+tc+2]=a12; Xs[(tr+1)*129+tc+3]=a13;
  __syncthreads();
  const float* W2 = wt + (8+m)*16384;
  a00=0;a01=0;a02=0;a03=0; a10=0;a11=0;a12=0;a13=0;
  for (int c=0;c<HCH;c++){
    float4 w4 = *(const float4*)(W2 + c*128 + tc);
    float x0 = Xs[tr*129 + c];
    float x1 = Xs[(tr+1)*129 + c];
    a00 += x0*w4.x; a01 += x0*w4.y; a02 += x0*w4.z; a03 += x0*w4.w;
    a10 += x1*w4.x; a11 += x1*w4.y; a12 += x1*w4.z; a13 += x1*w4.w;
  }
  bf16* out2 = m ? TKw16 : TQw16;
  {
    unsigned* o0 = (unsigned*)(out2 + (rt+tr  )*HCH + tc);
    unsigned* o1 = (unsigned*)(out2 + (rt+tr+1)*HCH + tc);
    o0[0]=pack2(a00,a01); o0[1]=pack2(a02,a03);
    o1[0]=pack2(a10,a11); o1[1]=pack2(a12,a13);
  }
}

// ------------------------------------------------- k25: fused KNN (blocks 0..63) + ligand LN/proj (64..127)
__global__ __launch_bounds__(256) void k25_small(
    const float* __restrict__ cvt, const int* __restrict__ batch, const float* __restrict__ wt,
    int* __restrict__ nbr, float* __restrict__ lf, bf16* __restrict__ Klw16, bf16* __restrict__ Vlw16)
{
  int b = blockIdx.x, tid = threadIdx.x;
  if (b < 64){
    int wave = tid>>6, lane = tid&63;
    int n = b*4 + wave;
    float cx = cvt[O_RESX+(n*NCA+1)*3+0];
    float cy = cvt[O_RESX+(n*NCA+1)*3+1];
    float cz = cvt[O_RESX+(n*NCA+1)*3+2];
    int bn = batch[n];
    float d2v[4]; int idv[4];
    #pragma unroll
    for (int t=0;t<4;t++){
      int j = lane + 64*t;
      float jx = cvt[O_RESX+(j*NCA+1)*3+0];
      float jy = cvt[O_RESX+(j*NCA+1)*3+1];
      float jz = cvt[O_RESX+(j*NCA+1)*3+2];
      float dx=cx-jx, dy=cy-jy, dz=cz-jz;
      float d2 = dx*dx+dy*dy+dz*dz;
      bool bad = (batch[j]!=bn) || (j==n);
      d2v[t] = bad ? INFINITY : d2;
      idv[t] = j;
    }
    for (int k=0;k<KNNK;k++){
      float dm = d2v[0]; int im = idv[0];
      #pragma unroll
      for (int t=1;t<4;t++)
        if (d2v[t]<dm || (d2v[t]==dm && idv[t]<im)){ dm=d2v[t]; im=idv[t]; }
      #pragma unroll
      for (int off=1; off<64; off<<=1){
        float dn = __shfl_xor(dm, off);
        int   in = __shfl_xor(im, off);
        if (dn<dm || (dn==dm && in<im)){ dm=dn; im=in; }
      }
      if (lane==0) nbr[n*KNNK+k] = im;
      #pragma unroll
      for (int t=0;t<4;t++) if (idv[t]==im) d2v[t] = INFINITY;
    }
    return;
  }
  __shared__ float x2[2][HCH];
  __shared__ float sred2[2][2];
  int row = tid>>7, t = tid&127;
  int rb = (b-64)*2 + row;
  float v = cvt[O_LFEAT + rb*HCH + t];
  float s=v;
  for (int off=1; off<64; off<<=1) s += __shfl_xor(s, off);
  if ((t&63)==0) sred2[row][t>>6]=s;
  __syncthreads();
  float mu=(sred2[row][0]+sred2[row][1])*(1.f/HCH);
  __syncthreads();
  float d=v-mu; s=d*d;
  for (int off=1; off<64; off<<=1) s += __shfl_xor(s, off);
  if ((t&63)==0) sred2[row][t>>6]=s;
  __syncthreads();
  float var=(sred2[row][0]+sred2[row][1])*(1.f/HCH);
  float xh = d*rsqrtf(var+1e-5f)*cvt[O_LN1G+t] + cvt[O_LN1B+t];
  x2[row][t]=xh; lf[rb*HCH+t]=xh;
  __syncthreads();
  const float* WKlt = wt + 4*16384;
  const float* WVlt = wt + 5*16384;
  float aK=0.f, aV=0.f;
  for (int c=0;c<HCH;c++){
    float xc=x2[row][c];
    aK += xc*WKlt[c*128+t];
    aV += xc*WVlt[c*128+t];
  }
  Klw16[rb*HCH+t]=__float2bfloat16(aK);
  Vlw16[rb*HCH+t]=__float2bfloat16(aV);
}

// ------------------------------------------------- k3: fused residue-edge, XCD-swizzled, bf16 LDS
// blockIdx b: rr = b & 255, slot = b >> 8. LDS rows: 64 data u32 + 2 pad, stride 66.
__global__ __launch_bounds__(256) void k3_edge(
    const float* __restrict__ cvt, const int* __restrict__ res_S, const int* __restrict__ nbr,
    const bf16* __restrict__ Qw16, const bf16* __restrict__ Kw16,
    const bf16* __restrict__ TQw16, const bf16* __restrict__ TKw16,
    const bf16* __restrict__ Vw16, const float* __restrict__ cT, const float* __restrict__ sigT,
    float* __restrict__ r_ws, bf16* __restrict__ aVe16, float* __restrict__ dXe)
{
  __shared__ unsigned Bq[14*66], Bk[14*66], Tq[14*66], Tk[14*66];
  __shared__ float LG[784], FR[196];
  __shared__ float tw2s[128], tb2s[1], Xr[42], Xc[42], amr[14], amc[14], rpart[56], cnts[2];
  unsigned* Vc = Tq;   // Tq dead after logits/fa phase

  int b = blockIdx.x, tid = threadIdx.x;
  int rr = b & 255, slot = b >> 8;
  int e  = (slot < 8) ? (rr*8 + slot) : (2048 + rr);
  int cc = (slot < 8) ? (nbr[rr*8 + slot] & 255) : rr;

  const unsigned* Q32  = (const unsigned*)Qw16;
  const unsigned* K32  = (const unsigned*)Kw16;
  const unsigned* TQ32 = (const unsigned*)TQw16;
  const unsigned* TK32 = (const unsigned*)TKw16;
  const unsigned* V32  = (const unsigned*)Vw16;

  for (int i=tid;i<NCA*64;i+=256){       // 896 u32 per tensor (14 rows x 64 u32)
    int p=i>>6, k=i&63;
    Bq[p*66+k]=Q32[rr*896+i];  Bk[p*66+k]=K32[cc*896+i];
    Tq[p*66+k]=TQ32[rr*896+i]; Tk[p*66+k]=TK32[cc*896+i];
  }
  if (tid < 128) tw2s[tid]=cvt[O_TIW2+tid];
  if (tid == 128) tb2s[0]=cvt[O_TIB2];
  if (tid >= 136 && tid < 178){
    int i=tid-136; int p=i/3, jx=i%3;
    Xr[i] = cvt[O_RESX+(rr*NCA+p)*3+jx];
    Xc[i] = cvt[O_RESX+(cc*NCA+p)*3+jx];
  }
  if (tid >= 242 && tid < 242+NCA){
    int p=tid-242;
    amr[p] = (p < ccount(res_S[rr])) ? 1.f : 0.f;
    amc[p] = (p < ccount(res_S[cc])) ? 1.f : 0.f;
  }
  __syncthreads();

  if (tid < 196){
    int p = tid/14, q = tid%14;
    float dx=Xr[p*3]-Xc[q*3], dy=Xr[p*3+1]-Xc[q*3+1], dz=Xr[p*3+2]-Xc[q*3+2];
    float d = sqrtf(fmaxf(dx*dx+dy*dy+dz*dz, 1e-12f));
    int i0 = (int)(fminf(d, DMAXT)*TSCALE + 0.5f);
    float4 sg = ((const float4*)sigT)[i0];
    const float4* crow = (const float4*)(cT + i0*128);
    float fa = tb2s[0];
    #pragma unroll 8
    for (int j=0;j<32;j++){
      float4 cb = crow[j];
      unsigned ta=Tq[p*66+2*j], tb2_=Tq[p*66+2*j+1];
      unsigned ka=Tk[q*66+2*j], kb =Tk[q*66+2*j+1];
      int o = 4*j;
      fa += fmaxf(bflo(ta)+bflo(ka)+cb.x, 0.f)*tw2s[o  ];
      fa += fmaxf(bfhi(ta)+bfhi(ka)+cb.y, 0.f)*tw2s[o+1];
      fa += fmaxf(bflo(tb2_)+bflo(kb)+cb.z, 0.f)*tw2s[o+2];
      fa += fmaxf(bfhi(tb2_)+bfhi(kb)+cb.w, 0.f)*tw2s[o+3];
    }
    float qk0=0,qk1=0,qk2=0,qk3=0;
    #pragma unroll
    for (int j=0;j<16;j++){
      unsigned a0=Bq[p*66+j],    b0=Bk[q*66+j];
      unsigned a1=Bq[p*66+16+j], b1=Bk[q*66+16+j];
      unsigned a2=Bq[p*66+32+j], b2=Bk[q*66+32+j];
      unsigned a3=Bq[p*66+48+j], b3=Bk[q*66+48+j];
      qk0 += bflo(a0)*bflo(b0) + bfhi(a0)*bfhi(b0);
      qk1 += bflo(a1)*bflo(b1) + bfhi(a1)*bfhi(b1);
      qk2 += bflo(a2)*bflo(b2) + bfhi(a2)*bfhi(b2);
      qk3 += bflo(a3)*bflo(b3) + bfhi(a3)*bfhi(b3);
    }
    const float isq = 0.17677669529663687f;
    LG[0*196+tid] = qk0*isq + sg.x;
    LG[1*196+tid] = qk1*isq + sg.y;
    LG[2*196+tid] = qk2*isq + sg.z;
    LG[3*196+tid] = qk3*isq + sg.w;
    FR[tid] = fa;
  }
  __syncthreads();   // Tq dead; Vc alias staged next

  for (int i=tid;i<NCA*64;i+=256){
    int p=i>>6, k=i&63;
    Vc[p*66+k]=V32[cc*896+i];
  }
  if (tid < 56){
    int h=tid/14, pp=tid%14;
    float ap = amr[pp];
    float row[NCA];
    float s=0;
    #pragma unroll
    for (int qq=0;qq<NCA;qq++){ row[qq]=LG[h*196+pp*14+qq]; s += row[qq]*amc[qq]; }
    rpart[h*14+pp] = s*ap;
    float m=-INFINITY;
    #pragma unroll
    for (int qq=0;qq<NCA;qq++) m=fmaxf(m,row[qq]);
    float sum=0;
    #pragma unroll
    for (int qq=0;qq<NCA;qq++){ row[qq]=expf(row[qq]-m); sum+=row[qq]; }
    float inv=1.f/sum, s2=0;
    #pragma unroll
    for (int qq=0;qq<NCA;qq++){ row[qq]=row[qq]*inv*ap*amc[qq]; s2+=row[qq]; }
    float inv2=1.f/(s2+1e-7f);
    #pragma unroll
    for (int qq=0;qq<NCA;qq++) LG[h*196+pp*14+qq]=row[qq]*inv2;
  }
  if (tid == 56){
    float sr=0, sc=0;
    for (int i=0;i<NCA;i++){ sr+=amr[i]; sc+=amc[i]; }
    cnts[0]=sr; cnts[1]=sc;
  }
  __syncthreads();
  if (tid < NH){
    float s=0;
    for (int pp=0;pp<NCA;pp++) s += rpart[tid*14+pp];
    r_ws[e*NH+tid] = s/(cnts[0]*cnts[1]);
  }
  if (tid < 196){
    int p=tid/14, q=tid%14;
    float ma = 0.25f*(LG[p*14+q] + LG[196+p*14+q] + LG[392+p*14+q] + LG[588+p*14+q]);
    FR[tid] *= ma;
  }
  __syncthreads();
  if (tid < NCA){
    int pp=tid;
    float ax=0, ay=0, az=0;
    #pragma unroll
    for (int qq=0;qq<NCA;qq++){
      float dx=Xr[pp*3]-Xc[qq*3], dy=Xr[pp*3+1]-Xc[qq*3+1], dz=Xr[pp*3+2]-Xc[qq*3+2];
      float nrm = sqrtf(fmaxf(dx*dx+dy*dy+dz*dz,1e-12f));
      float sc = FR[pp*14+qq]/(nrm+1e-5f);
      ax += sc*dx; ay += sc*dy; az += sc*dz;
    }
    dXe[(e*NCA+pp)*3+0]=ax; dXe[(e*NCA+pp)*3+1]=ay; dXe[(e*NCA+pp)*3+2]=az;
  }
  #pragma unroll
  for (int rep=0;rep<7;rep++){
    int jdx = rep*256 + tid;
    int h = jdx/448, rem = jdx%448;
    int pp = rem>>5, dd = rem&31;
    int pi = h*16 + (dd>>1);
    int hi = dd & 1;
    float acc=0;
    #pragma unroll
    for (int qq=0;qq<NCA;qq++){
      unsigned v = Vc[qq*66 + pi];
      acc += LG[h*196+pp*14+qq] * (hi ? bfhi(v) : bflo(v));
    }
    aVe16[e*1792 + jdx] = __float2bfloat16(acc);
  }
}

// ------------------------------------------------- k4: per-residue beta + updH + WO + dX
__global__ __launch_bounds__(128) void k4_agg(
    const float* __restrict__ cvt, const int* __restrict__ res_S, const int* __restrict__ inv_row,
    const float* __restrict__ r_ws, const bf16* __restrict__ aVe16, const float* __restrict__ dXe,
    const float* __restrict__ resHn, const float* __restrict__ wt, const int* __restrict__ flag,
    float* __restrict__ resH2, float* __restrict__ resX2, void* __restrict__ d_out)
{
  int n = blockIdx.x, tid = threadIdx.x;
  __shared__ float beta[9][NH];
  __shared__ float betam[9];
  __shared__ float Xs[NCA][HCH];
  if (tid < NH){
    int h = tid;
    float rv[9], m=-INFINITY;
    #pragma unroll
    for (int k=0;k<9;k++){
      int ek = (k<KNNK)? n*KNNK+k : NKE+n;
      rv[k] = r_ws[ek*NH+h];
      m = fmaxf(m, rv[k]);
    }
    float s=0;
    #pragma unroll
    for (int k=0;k<9;k++){ rv[k]=expf(rv[k]-m); s+=rv[k]; }
    #pragma unroll
    for (int k=0;k<9;k++) beta[k][h]=rv[k]/s;
  }
  __syncthreads();
  if (tid < 9) betam[tid] = 0.25f*(beta[tid][0]+beta[tid][1]+beta[tid][2]+beta[tid][3]);
  int h = tid>>5, dd = tid&31;
  float bh[9];
  #pragma unroll
  for (int k=0;k<9;k++) bh[k]=beta[k][h];
  for (int p=0;p<NCA;p++){
    float u=0;
    #pragma unroll
    for (int k=0;k<9;k++){
      int ek = (k<KNNK)? n*KNNK+k : NKE+n;
      u += bh[k]*b2f(aVe16[ek*1792 + h*448 + p*32 + dd]);
    }
    Xs[p][tid] = sspf(u);
  }
  __syncthreads();
  const float* WOt = wt + 3*16384;
  float acc[NCA];
  #pragma unroll
  for (int p=0;p<NCA;p++) acc[p]=0.f;
  for (int c=0;c<HCH;c++){
    float w = WOt[c*128+tid];
    #pragma unroll
    for (int p=0;p<NCA;p++) acc[p] += Xs[p][c]*w;
  }
  int cnt = ccount(res_S[n]);
  for (int p=0;p<NCA;p++){
    float am = (p<cnt)?1.f:0.f;
    float outv = (resHn[(n*NCA+p)*HCH+tid] + acc[p])*am;
    resH2[(n*NCA+p)*HCH+tid] = outv;
  }
  if (tid < NCA*3){
    int isbf = *flag;
    int p=tid/3, jx=tid%3;
    float s=0;
    #pragma unroll
    for (int k=0;k<9;k++){
      int ek=(k<KNNK)? n*KNNK+k : NKE+n;
      s += betam[k]*dXe[(ek*NCA+p)*3+jx];
    }
    float base = cvt[O_RESX+(n*NCA+p)*3+jx];
    float v = (inv_row[n]>=0) ? base + fminf(fmaxf(s,-3.f),3.f) : base;
    resX2[(n*NCA+p)*3+jx] = v;
    storeOut(d_out, isbf, OUTX_OFF + (n*NCA+p)*3+jx, v);
  }
}

// ------------------------------------------------- k6: fused ligand-edge (logits + softmaxes + aVr/aVlg)
__global__ __launch_bounds__(256) void k6_lig(
    const float* __restrict__ cvt, const int* __restrict__ res_S,
    const int* __restrict__ row1, const int* __restrict__ col1,
    const float* __restrict__ resX2, const bf16* __restrict__ Qw16, const bf16* __restrict__ Klw16,
    const bf16* __restrict__ Vw16, const bf16* __restrict__ Vlw16, const float* __restrict__ sig1T,
    float* __restrict__ r1_ws, float* __restrict__ aVr, float* __restrict__ aVlg)
{
  __shared__ __align__(16) float S[10042];
  float* Bq  = S;
  float* Bk  = S + 1848;
  float* LG  = S;
  float* Vl  = S + 1848;
  float* ALs = S + 6104;
  float* Vr  = S + 7896;
  float* EX  = S + 9744;
  float* Xr = EX;
  float* Lp = EX + 42;
  float* amr = EX + 138;
  float* lm  = EX + 152;
  float* s2r = EX + 184;
  float* rpart = EX + 240;
  float* cnts  = EX + 296;
  int e = blockIdx.x, tid = threadIdx.x;
  int rr = row1[e] & 255, cb = col1[e] & 3;

  for (int i=tid;i<NCA*HCH;i+=256){ int p=i>>7,c=i&127; Bq[p*132+c]=b2f(Qw16[rr*1792+i]); Vr[p*132+c]=b2f(Vw16[rr*1792+i]); }
  for (int i=tid;i<LC*HCH;i+=256){ int q=i>>7,c=i&127; Bk[q*133+c]=b2f(Klw16[cb*LC*HCH+i]); }
  if (tid >= 8 && tid < 50){ int i=tid-8; int p=i/3,jx=i%3; Xr[i]=resX2[(rr*NCA+p)*3+jx]; }
  if (tid >= 64 && tid < 160){ int i=tid-64; int q=i/3,jx=i%3; Lp[i]=cvt[O_LPOS+(cb*LC+q)*3+jx]; }
  if (tid >= 160 && tid < 160+NCA) amr[tid-160]=((tid-160) < ccount(res_S[rr]))?1.f:0.f;
  if (tid >= 192 && tid < 224) lm[tid-192]=cvt[O_LMASK + cb*LC + tid-192];
  __syncthreads();

  float l0[2][4];
  int npair = (tid < 192) ? 2 : 1;
  for (int w=0; w<npair; w++){
    int pair = tid + w*256;
    int p = pair>>5, q = pair&31;
    float dx=Xr[p*3]-Lp[q*3], dy=Xr[p*3+1]-Lp[q*3+1], dz=Xr[p*3+2]-Lp[q*3+2];
    float d = sqrtf(fmaxf(dx*dx+dy*dy+dz*dz,1e-12f));
    int i0 = (int)(fminf(d, DMAXT)*TSCALE + 0.5f);
    float4 sg = ((const float4*)sig1T)[i0];
    float q0=0,q1=0,q2=0,q3=0;
    #pragma unroll
    for (int dd=0;dd<DH;dd++){
      q0 += Bq[p*132+dd]   *Bk[q*133+dd];
      q1 += Bq[p*132+32+dd]*Bk[q*133+32+dd];
      q2 += Bq[p*132+64+dd]*Bk[q*133+64+dd];
      q3 += Bq[p*132+96+dd]*Bk[q*133+96+dd];
    }
    const float isq=0.17677669529663687f;
    l0[w][0]=q0*isq+sg.x; l0[w][1]=q1*isq+sg.y; l0[w][2]=q2*isq+sg.z; l0[w][3]=q3*isq+sg.w;
  }
  __syncthreads();
  for (int w=0; w<npair; w++){
    int pair = tid + w*256;
    LG[0*448+pair]=l0[w][0]; LG[1*448+pair]=l0[w][1]; LG[2*448+pair]=l0[w][2]; LG[3*448+pair]=l0[w][3];
  }
  for (int i=tid;i<LC*HCH;i+=256){ int q=i>>7,c=i&127; Vl[q*132+c]=b2f(Vlw16[cb*LC*HCH+i]); }
  __syncthreads();

  if (tid < 56){
    int h=tid/14, pp=tid%14;
    float ap=amr[pp];
    float s=0, m=-INFINITY;
    for (int qq=0;qq<LC;qq++){ float v=LG[h*448+pp*32+qq]; s+=v*lm[qq]; m=fmaxf(m,v); }
    rpart[h*14+pp]=s*ap;
    float sum=0;
    for (int qq=0;qq<LC;qq++) sum+=expf(LG[h*448+pp*32+qq]-m);
    float inv=1.f/sum, s2=0;
    for (int qq=0;qq<LC;qq++) s2 += expf(LG[h*448+pp*32+qq]-m)*inv*ap*lm[qq];
    s2r[h*14+pp] = s2/(s2+1e-7f);
  }
  if (tid==56){
    float sr=0,sl=0;
    for(int i=0;i<NCA;i++) sr+=amr[i];
    for(int i=0;i<LC;i++) sl+=lm[i];
    cnts[0]=sr; cnts[1]=sl;
  }
  __syncthreads();
  if (tid < NH){
    float s=0; for (int pp=0;pp<NCA;pp++) s+=rpart[tid*14+pp];
    r1_ws[e*NH+tid]=s/(cnts[0]*cnts[1]);
  }
  if (tid < NH*LC){
    int h=tid>>5, qq=tid&31;
    float m=-INFINITY;
    for (int pp=0;pp<NCA;pp++) m=fmaxf(m,LG[h*448+pp*32+qq]);
    float sum=0;
    for (int pp=0;pp<NCA;pp++) sum+=expf(LG[h*448+pp*32+qq]-m);
    float inv=1.f/sum;
    float lq=lm[qq];
    for (int pp=0;pp<NCA;pp++){
      float a=expf(LG[h*448+pp*32+qq]-m)*inv*amr[pp]*lq;
      ALs[h*448+pp*32+qq]=a/(s2r[h*14+pp]+1e-7f);
    }
  }
  __syncthreads();
  if (tid < 56){
    int h=tid/14, pp=tid%14;
    float ap=amr[pp];
    float m=-INFINITY;
    for (int qq=0;qq<LC;qq++) m=fmaxf(m,LG[h*448+pp*32+qq]);
    float row[LC];
    float sum=0;
    for (int qq=0;qq<LC;qq++){ row[qq]=expf(LG[h*448+pp*32+qq]-m); sum+=row[qq]; }
    float inv=1.f/sum, s2=0;
    for (int qq=0;qq<LC;qq++){ row[qq]=row[qq]*inv*ap*lm[qq]; s2+=row[qq]; }
    float inv2=1.f/(s2+1e-7f);
    for (int qq=0;qq<LC;qq++) LG[h*448+pp*32+qq]=row[qq]*inv2;
  }
  __syncthreads();
  for (int j=tid;j<NH*NCA*DH;j+=256){
    int h=j/448, rem=j%448, pp=rem>>5, dd=rem&31;
    float acc=0;
    #pragma unroll
    for (int qq=0;qq<LC;qq++) acc += LG[h*448+pp*32+qq]*Vl[qq*132+h*32+dd];
    aVr[e*1792+j]=acc;
  }
  for (int j=tid;j<NH*LC*DH;j+=256){
    int h=j>>10, rem=j&1023, qq=rem>>5, dd=rem&31;
    float acc=0;
    #pragma unroll
    for (int pp=0;pp<NCA;pp++) acc += ALs[h*448+pp*32+qq]*Vr[pp*132+h*32+dd];
    aVlg[e*4096+j]=acc;
  }
}

// ------------------------------------------------- k78: finalize res_H3 (blocks 0..255) + lf2 (256..383)
__global__ __launch_bounds__(128) void k78_final(
    const int* __restrict__ inv_row, const int* __restrict__ res_S, const int* __restrict__ col1,
    const float* __restrict__ resH2, const float* __restrict__ aVr,
    const float* __restrict__ r1_ws, const float* __restrict__ aVlg, const float* __restrict__ lf,
    const float* __restrict__ wt, const int* __restrict__ flag, void* __restrict__ d_out)
{
  int bb = blockIdx.x, tid = threadIdx.x;
  if (bb < 256){
    int n = bb;
    int e = inv_row[n];
    __shared__ float G[NCA][HCH];
    if (e>=0){
      for (int j=tid;j<NCA*HCH;j+=128){
        int h=j/448, rem=j%448, pp=rem>>5, dd=rem&31;
        G[pp][h*DH+dd] = sspf(aVr[e*1792+j]);
      }
    }
    __syncthreads();
    float acc[NCA];
    #pragma unroll
    for (int p=0;p<NCA;p++) acc[p]=0.f;
    if (e>=0){
      const float* WOlt = wt + 6*16384;
      for (int c=0;c<HCH;c++){
        float w=WOlt[c*128+tid];
        #pragma unroll
        for (int p=0;p<NCA;p++) acc[p]+=G[p][c]*w;
      }
    }
    int cnt=ccount(res_S[n]);
    int isbf = *flag;
    for (int p=0;p<NCA;p++){
      float am=(p<cnt)?1.f:0.f;
      float v=(resH2[(n*NCA+p)*HCH+tid]+acc[p])*am;
      storeOut(d_out, isbf, (n*NCA+p)*HCH+tid, v);
    }
    return;
  }
  int rb = bb - 256;
  int b = rb>>5, q = rb&31;
  __shared__ float bw[NE1][NH];
  __shared__ float xs[HCH];
  if (tid<NH){
    int h=tid;
    float m=-INFINITY;
    for (int e=0;e<NE1;e++) if ((col1[e]&3)==b) m=fmaxf(m, r1_ws[e*NH+h]);
    float s=0;
    for (int e=0;e<NE1;e++) if ((col1[e]&3)==b) s+=expf(r1_ws[e*NH+h]-m);
    for (int e=0;e<NE1;e++) bw[e][h] = ((col1[e]&3)==b)? expf(r1_ws[e*NH+h]-m)/s : 0.f;
  }
  __syncthreads();
  int h=tid>>5, dd=tid&31;
  float u=0;
  for (int e=0;e<NE1;e++) u += bw[e][h]*aVlg[e*4096 + h*1024 + q*32 + dd];
  xs[tid]=sspf(u);
  __syncthreads();
  const float* WOl1t = wt + 7*16384;
  float acc=0;
  for (int c=0;c<HCH;c++) acc += xs[c]*WOl1t[c*128+tid];
  float v = lf[rb*HCH+tid] + acc;
  storeOut(d_out, *flag, OUTL_OFF + rb*HCH+tid, v);
}

// ================================================================ launch
extern "C" void kernel_launch(void* const* d_in, const int* in_sizes, int n_in,
                              void* d_out, int out_size, void* d_ws, size_t ws_size,
                              hipStream_t stream)
{
  const int* res_S = (const int*)d_in[29];
  const int* batch = (const int*)d_in[30];
  const int* row1  = (const int*)d_in[32];
  const int* col1  = (const int*)d_in[33];

  float* wsf = (float*)d_ws;
  size_t o = 0;
  int*   flag    = (int*)(wsf + o); o += 4;
  float* cvt     = wsf + o; o += CVT_RSV;
  float* wt      = wsf + o; o += 10*16384;
  int*   inv_row = (int*)(wsf + o); o += 256;
  int*   nbr     = (int*)(wsf + o); o += NRES*KNNK;
  float* resHn   = wsf + o; o += NROWS*HCH;
  bf16*  Qw16    = (bf16*)(wsf + o); o += NROWS*HCH/2;
  bf16*  Kw16    = (bf16*)(wsf + o); o += NROWS*HCH/2;
  bf16*  Vw16    = (bf16*)(wsf + o); o += NROWS*HCH/2;
  bf16*  TQw16   = (bf16*)(wsf + o); o += NROWS*HCH/2;
  bf16*  TKw16   = (bf16*)(wsf + o); o += NROWS*HCH/2;
  float* r_ws    = wsf + o; o += NEDGE*NH;
  bf16*  aVe16   = (bf16*)(wsf + o); o += (size_t)NEDGE*1792/2;
  float* dXe     = wsf + o; o += NEDGE*NCA*3;
  float* resH2   = wsf + o; o += NROWS*HCH;
  float* resX2   = wsf + o; o += NRES*NCA*3;
  float* lf      = wsf + o; o += 4*LC*HCH;
  bf16*  Klw16   = (bf16*)(wsf + o); o += 4*LC*HCH/2;
  bf16*  Vlw16   = (bf16*)(wsf + o); o += 4*LC*HCH/2;
  float* r1w     = wsf + o; o += NE1*NH;
  float* aVrw    = wsf + o; o += NE1*1792;
  float* aVlgw   = wsf + o; o += NE1*4096;
  float* cT      = wsf + o; o += (size_t)NT*128;
  float* sigT    = wsf + o; o += NT*4;
  float* sig1T   = wsf + o; o += NT*4;

  kdet<<<1, 64, 0, stream>>>((const unsigned*)d_in[0], flag);
  kcvt<<<(TOTCVT+255)/256, 256, 0, stream>>>(flag,
      d_in[0],d_in[1],d_in[2],d_in[3],d_in[4],d_in[5],d_in[6],d_in[7],d_in[8],
      d_in[9],d_in[10],d_in[11],d_in[12],d_in[13],d_in[14],d_in[15],d_in[16],
      d_in[17],d_in[18],d_in[19],d_in[20],d_in[21],d_in[22],d_in[23],d_in[24],
      d_in[25],d_in[26],d_in[27],d_in[28], cvt);
  ktab<<<NT, 128, 0, stream>>>(cvt, cT, sigT, sig1T);
  k0_prep<<<641, 256, 0, stream>>>(cvt, row1, wt, inv_row);
  kProj<<<dim3(NROWS/16, 3), 256, 0, stream>>>(cvt, wt, resHn, Qw16, Kw16, Vw16, TQw16, TKw16);
  k25_small<<<128, 256, 0, stream>>>(cvt, batch, wt, nbr, lf, Klw16, Vlw16);
  k3_edge<<<NEDGE, 256, 0, stream>>>(cvt, res_S, nbr, Qw16, Kw16, TQw16, TKw16, Vw16, cT, sigT,
                                     r_ws, aVe16, dXe);
  k4_agg<<<NRES, 128, 0, stream>>>(cvt, res_S, inv_row, r_ws, aVe16, dXe, resHn, wt, flag,
                                   resH2, resX2, d_out);
  k6_lig<<<NE1, 256, 0, stream>>>(cvt, res_S, row1, col1, resX2, Qw16, Klw16, Vw16, Vlw16, sig1T,
                                  r1w, aVrw, aVlgw);
  k78_final<<<384, 128, 0, stream>>>(inv_row, res_S, col1, resH2, aVrw, r1w, aVlgw, lf,
                                     wt, flag, d_out);
}

// Round 9
// 279.310 us; speedup vs baseline: 1.2941x; 1.1198x over previous
//
#include <hip/hip_runtime.h>
#include <hip/hip_bf16.h>
#include <math.h>

typedef __hip_bfloat16 bf16;

#define NRES 256
#define LC   32
#define HCH  128
#define ECH  64
#define NH   4
#define NCA  14
#define KNNK 8
#define DH   32
#define NKE  (NRES*KNNK)      // 2048
#define NEDGE (NKE+NRES)      // 2304
#define NE1  64
#define NROWS (NRES*NCA)      // 3584

// distance tables: nearest-neighbor, h=1/256, domain [0,12]
#define NT     3073
#define TSCALE 256.0f
#define DMAXT  12.0f

// ---- fp32 converted-input region offsets (floats) ----
#define O_RESH   0
#define O_RESX   458752
#define O_LPOS   469504
#define O_LFEAT  469888
#define O_LMASK  486272
#define O_LNG    486400
#define O_LNB    486528
#define O_LN1G   486656
#define O_LN1B   486784
#define O_WQ     486912
#define O_WK     503296
#define O_WV     519680
#define O_WKL    536064
#define O_WVL    552448
#define O_WO     568832
#define O_WOL    585216
#define O_WOL1   601600
#define O_TIW1   617984
#define O_TIB1   658944
#define O_TIW2   659072
#define O_TIB2   659200
#define O_SDW1   659204
#define O_SDB1   667396
#define O_SDW2   667524
#define O_SDB2   668036
#define O_SD1W1  668040
#define O_SD1B1  676232
#define O_SD1W2  676360
#define O_SD1B2  676872
#define TOTCVT   676876
#define CVT_RSV  676880

#define OUTX_OFF 458752
#define OUTL_OFF 469504

__constant__ int c_counts[21] = {14,5,11,8,8,6,9,9,4,10,8,8,9,8,11,7,6,7,14,12,7};

__device__ __forceinline__ float b2f(bf16 x){ return __bfloat162float(x); }
__device__ __forceinline__ float sspf(float x){
  return fmaxf(x,0.f) + log1pf(expf(-fabsf(x))) - 0.6931471805599453f;
}
__device__ __forceinline__ float bflo(unsigned u){ return __uint_as_float(u<<16); }
__device__ __forceinline__ float bfhi(unsigned u){ return __uint_as_float(u & 0xffff0000u); }
__device__ __forceinline__ unsigned short f2bs(float v){ bf16 b=__float2bfloat16(v); return *(unsigned short*)&b; }
__device__ __forceinline__ unsigned pack2(float a, float b){
  return (unsigned)f2bs(a) | ((unsigned)f2bs(b)<<16);
}
__device__ __forceinline__ int ccount(int s){ return c_counts[s<0?0:(s>20?20:s)]; }
__device__ __forceinline__ void storeOut(void* out, int isbf, int idx, float v){
  if (isbf) ((bf16*)out)[idx] = __float2bfloat16(v);
  else      ((float*)out)[idx] = v;
}

// ---------------------------------------------------------------- kcvt: inputs -> fp32 (flag computed per-block)
__global__ __launch_bounds__(256) void kcvt(
    const void* s0,const void* s1,const void* s2,const void* s3,const void* s4,
    const void* s5,const void* s6,const void* s7,const void* s8,const void* s9,
    const void* s10,const void* s11,const void* s12,const void* s13,const void* s14,
    const void* s15,const void* s16,const void* s17,const void* s18,const void* s19,
    const void* s20,const void* s21,const void* s22,const void* s23,const void* s24,
    const void* s25,const void* s26,const void* s27,const void* s28,
    float* __restrict__ dst, int* __restrict__ flag)
{
  __shared__ int sflag;
  int tid = threadIdx.x;
  if (tid < 64){
    unsigned w = ((const unsigned*)s0)[tid];
    unsigned lo = w & 0xFFFFu;
    int ee = (lo >> 7) & 0xFF;
    int good = (lo == 0u) || (ee >= 121 && ee <= 133);
    unsigned long long m = __ballot(good);
    if (tid == 0){
      sflag = (__popcll(m) >= 40) ? 1 : 0;
      if (blockIdx.x == 0) flag[0] = sflag;
    }
  }
  __syncthreads();
  int isbf = sflag;
  int g = blockIdx.x*256 + tid;
  if (g >= TOTCVT) return;
  const void* src; int l;
  if      (g < O_RESX ) { src=s0;  l=g; }
  else if (g < O_LPOS ) { src=s1;  l=g-O_RESX; }
  else if (g < O_LFEAT) { src=s2;  l=g-O_LPOS; }
  else if (g < O_LMASK) { src=s3;  l=g-O_LFEAT; }
  else if (g < O_LNG  ) { src=s4;  l=g-O_LMASK; }
  else if (g < O_LNB  ) { src=s5;  l=g-O_LNG; }
  else if (g < O_LN1G ) { src=s6;  l=g-O_LNB; }
  else if (g < O_LN1B ) { src=s7;  l=g-O_LN1G; }
  else if (g < O_WQ   ) { src=s8;  l=g-O_LN1B; }
  else if (g < O_WK   ) { src=s9;  l=g-O_WQ; }
  else if (g < O_WV   ) { src=s10; l=g-O_WK; }
  else if (g < O_WKL  ) { src=s11; l=g-O_WV; }
  else if (g < O_WVL  ) { src=s12; l=g-O_WKL; }
  else if (g < O_WO   ) { src=s13; l=g-O_WVL; }
  else if (g < O_WOL  ) { src=s14; l=g-O_WO; }
  else if (g < O_WOL1 ) { src=s15; l=g-O_WOL; }
  else if (g < O_TIW1 ) { src=s16; l=g-O_WOL1; }
  else if (g < O_TIB1 ) { src=s17; l=g-O_TIW1; }
  else if (g < O_TIW2 ) { src=s18; l=g-O_TIB1; }
  else if (g < O_TIB2 ) { src=s19; l=g-O_TIW2; }
  else if (g < O_SDW1 ) { src=s20; l=0; }
  else if (g < O_SDB1 ) { src=s21; l=g-O_SDW1; }
  else if (g < O_SDW2 ) { src=s22; l=g-O_SDB1; }
  else if (g < O_SDB2 ) { src=s23; l=g-O_SDW2; }
  else if (g < O_SD1W1) { src=s24; l=g-O_SDB2; }
  else if (g < O_SD1B1) { src=s25; l=g-O_SD1W1; }
  else if (g < O_SD1W2) { src=s26; l=g-O_SD1B1; }
  else if (g < O_SD1B2) { src=s27; l=g-O_SD1W2; }
  else                  { src=s28; l=g-O_SD1B2; }
  float v = isbf ? b2f(((const bf16*)src)[l]) : ((const float*)src)[l];
  dst[g] = v;
}

// ---------------------------------------------------------------- kprep: ktab (b<NT) + weight transpose + inv_row
__global__ __launch_bounds__(128) void kprep(const float* __restrict__ cvt, const int* __restrict__ row1,
    float* __restrict__ cT, float* __restrict__ sigT, float* __restrict__ sig1T,
    float* __restrict__ wt, int* __restrict__ inv_row)
{
  int b = blockIdx.x, o = threadIdx.x;
  if (b >= NT){
    int cb = b - NT;
    if (cb < 1280){
      int gid = cb*128 + o;
      int m = gid >> 14;
      int j = gid & 16383;
      int oo = j >> 7, c = j & 127;
      float v;
      switch(m){
        case 0: v = cvt[O_WQ  + j]; break;
        case 1: v = cvt[O_WK  + j]; break;
        case 2: v = cvt[O_WV  + j]; break;
        case 3: v = cvt[O_WO  + j]; break;
        case 4: v = cvt[O_WKL + j]; break;
        case 5: v = cvt[O_WVL + j]; break;
        case 6: v = cvt[O_WOL + j]; break;
        case 7: v = cvt[O_WOL1+ j]; break;
        case 8: v = cvt[O_TIW1 + oo*320 + c]; break;
        default:v = cvt[O_TIW1 + oo*320 + 128 + c]; break;
      }
      wt[m*16384 + c*128 + oo] = v;
    } else {
      for (int i=o;i<NRES;i+=128) inv_row[i] = -1;
      __syncthreads();
      if (o < NE1) inv_row[row1[o] & 255] = o;
    }
    return;
  }
  __shared__ float dr[64];
  __shared__ float W[128*65];
  __shared__ float h1[128], h1b[128];
  float d = (float)b * (1.0f/256.0f);
  const float step = 10.0f/63.0f;
  const float coef = -0.5f/(step*step);
  if (o < 64){ float t = d - step*(float)o; dr[o] = expf(coef*t*t); }
  for (int idx=o; idx<8192; idx+=128){ int oo=idx>>6, k=idx&63; W[oo*65+k] = cvt[O_TIW1 + oo*320 + 256 + k]; }
  __syncthreads();
  {
    float c = cvt[O_TIB1+o];
    for (int k=0;k<64;k++) c += dr[k]*W[o*65+k];
    cT[b*128+o] = c;
  }
  __syncthreads();
  for (int idx=o; idx<8192; idx+=128){ int oo=idx>>6, k=idx&63; W[oo*65+k] = cvt[O_SDW1 + idx]; }
  __syncthreads();
  {
    float a = cvt[O_SDB1+o];
    for (int k=0;k<64;k++) a += dr[k]*W[o*65+k];
    h1[o] = fmaxf(a,0.f);
  }
  __syncthreads();
  for (int idx=o; idx<8192; idx+=128){ int oo=idx>>6, k=idx&63; W[oo*65+k] = cvt[O_SD1W1 + idx]; }
  __syncthreads();
  {
    float a2 = cvt[O_SD1B1+o];
    for (int k=0;k<64;k++) a2 += dr[k]*W[o*65+k];
    h1b[o] = fmaxf(a2,0.f);
  }
  __syncthreads();
  if (o < 8){
    int h = o & 3;
    const float* hh = (o<4)? h1 : h1b;
    int wbase = (o<4)? O_SDW2 : O_SD1W2;
    int bbase = (o<4)? O_SDB2 : O_SD1B2;
    float s = cvt[bbase + h];
    for (int k=0;k<128;k++) s += hh[k]*cvt[wbase + h*128 + k];
    if (o<4) sigT[b*4+h] = s; else sig1T[b*4+h] = s;
  }
}

// ------------------------------------------------- kProjAll: b<672 LN+proj tiles; 672..735 KNN; 736..799 ligand
__global__ __launch_bounds__(256) void kProjAll(
    const float* __restrict__ cvt, const float* __restrict__ wt, const int* __restrict__ batch,
    float* __restrict__ resHn, bf16* __restrict__ Qw16, bf16* __restrict__ Kw16,
    bf16* __restrict__ Vw16, bf16* __restrict__ TQw16, bf16* __restrict__ TKw16,
    int* __restrict__ nbr, float* __restrict__ lf, bf16* __restrict__ Klw16, bf16* __restrict__ Vlw16)
{
  __shared__ float Xs[16*129];
  __shared__ float x2[2][HCH];
  __shared__ float sred2[2][2];
  int bb = blockIdx.x, tid = threadIdx.x;

  if (bb < 672){
    int m = bb / 224;
    int rt = (bb % 224) * 16;
    for (int i=tid; i<16*128; i+=256){
      int r=i>>7, c=i&127;
      Xs[r*129+c] = cvt[O_RESH + (rt+r)*HCH + c];
    }
    __syncthreads();
    {
      int wave = tid>>6, lane = tid&63;
      int r = wave*4 + (lane>>4);
      int cb = lane & 15;
      float s=0;
      #pragma unroll
      for (int j=0;j<8;j++) s += Xs[r*129 + cb + 16*j];
      #pragma unroll
      for (int off=1; off<16; off<<=1) s += __shfl_xor(s, off);
      float mu = s*(1.f/HCH);
      float q=0;
      #pragma unroll
      for (int j=0;j<8;j++){ float dv = Xs[r*129+cb+16*j]-mu; q += dv*dv; }
      #pragma unroll
      for (int off=1; off<16; off<<=1) q += __shfl_xor(q, off);
      float inv = rsqrtf(q*(1.f/HCH) + 1e-5f);
      #pragma unroll
      for (int j=0;j<8;j++){
        int c = cb + 16*j;
        float xh = (Xs[r*129+c]-mu)*inv*cvt[O_LNG+c] + cvt[O_LNB+c];
        Xs[r*129+c] = xh;
        if (m==0) resHn[(rt+r)*HCH+c] = xh;
      }
    }
    __syncthreads();
    int tc = (tid & 31) * 4;
    int tr = (tid >> 5) * 2;
    const float* W = wt + m*16384;
    float a00=0,a01=0,a02=0,a03=0, a10=0,a11=0,a12=0,a13=0;
    for (int c=0;c<HCH;c++){
      float4 w4 = *(const float4*)(W + c*128 + tc);
      float x0 = Xs[tr*129 + c];
      float x1 = Xs[(tr+1)*129 + c];
      a00 += x0*w4.x; a01 += x0*w4.y; a02 += x0*w4.z; a03 += x0*w4.w;
      a10 += x1*w4.x; a11 += x1*w4.y; a12 += x1*w4.z; a13 += x1*w4.w;
    }
    bf16* out = (m==0)? Qw16 : (m==1)? Kw16 : Vw16;
    {
      unsigned* o0 = (unsigned*)(out + (rt+tr  )*HCH + tc);
      unsigned* o1 = (unsigned*)(out + (rt+tr+1)*HCH + tc);
      o0[0]=pack2(a00,a01); o0[1]=pack2(a02,a03);
      o1[0]=pack2(a10,a11); o1[1]=pack2(a12,a13);
    }
    if (m == 2) return;
    __syncthreads();
    Xs[tr*129+tc]=a00; Xs[tr*129+tc+1]=a01; Xs[tr*129+tc+2]=a02; Xs[tr*129+tc+3]=a03;
    Xs[(tr+1)*129+tc]=a10; Xs[(tr+1)*129+tc+1]=a11; Xs[(tr+1)*129+tc+2]=a12; Xs[(tr+1)*129+tc+3]=a13;
    __syncthreads();
    const float* W2 = wt + (8+m)*16384;
    a00=0;a01=0;a02=0;a03=0; a10=0;a11=0;a12=0;a13=0;
    for (int c=0;c<HCH;c++){
      float4 w4 = *(const float4*)(W2 + c*128 + tc);
      float x0 = Xs[tr*129 + c];
      float x1 = Xs[(tr+1)*129 + c];
      a00 += x0*w4.x; a01 += x0*w4.y; a02 += x0*w4.z; a03 += x0*w4.w;
      a10 += x1*w4.x; a11 += x1*w4.y; a12 += x1*w4.z; a13 += x1*w4.w;
    }
    bf16* out2 = m ? TKw16 : TQw16;
    {
      unsigned* o0 = (unsigned*)(out2 + (rt+tr  )*HCH + tc);
      unsigned* o1 = (unsigned*)(out2 + (rt+tr+1)*HCH + tc);
      o0[0]=pack2(a00,a01); o0[1]=pack2(a02,a03);
      o1[0]=pack2(a10,a11); o1[1]=pack2(a12,a13);
    }
    return;
  }

  if (bb < 736){
    // KNN: one wave per residue
    int wave = tid>>6, lane = tid&63;
    int n = (bb-672)*4 + wave;
    float cx = cvt[O_RESX+(n*NCA+1)*3+0];
    float cy = cvt[O_RESX+(n*NCA+1)*3+1];
    float cz = cvt[O_RESX+(n*NCA+1)*3+2];
    int bn = batch[n];
    float d2v[4]; int idv[4];
    #pragma unroll
    for (int t=0;t<4;t++){
      int j = lane + 64*t;
      float jx = cvt[O_RESX+(j*NCA+1)*3+0];
      float jy = cvt[O_RESX+(j*NCA+1)*3+1];
      float jz = cvt[O_RESX+(j*NCA+1)*3+2];
      float dx=cx-jx, dy=cy-jy, dz=cz-jz;
      float d2 = dx*dx+dy*dy+dz*dz;
      bool bad = (batch[j]!=bn) || (j==n);
      d2v[t] = bad ? INFINITY : d2;
      idv[t] = j;
    }
    for (int k=0;k<KNNK;k++){
      float dm = d2v[0]; int im = idv[0];
      #pragma unroll
      for (int t=1;t<4;t++)
        if (d2v[t]<dm || (d2v[t]==dm && idv[t]<im)){ dm=d2v[t]; im=idv[t]; }
      #pragma unroll
      for (int off=1; off<64; off<<=1){
        float dn = __shfl_xor(dm, off);
        int   in = __shfl_xor(im, off);
        if (dn<dm || (dn==dm && in<im)){ dm=dn; im=in; }
      }
      if (lane==0) nbr[n*KNNK+k] = im;
      #pragma unroll
      for (int t=0;t<4;t++) if (idv[t]==im) d2v[t] = INFINITY;
    }
    return;
  }

  // ligand LN + Kl/Vl: 2 rows per block
  int row = tid>>7, t = tid&127;
  int rb = (bb-736)*2 + row;
  float v = cvt[O_LFEAT + rb*HCH + t];
  float s=v;
  for (int off=1; off<64; off<<=1) s += __shfl_xor(s, off);
  if ((t&63)==0) sred2[row][t>>6]=s;
  __syncthreads();
  float mu=(sred2[row][0]+sred2[row][1])*(1.f/HCH);
  __syncthreads();
  float d=v-mu; s=d*d;
  for (int off=1; off<64; off<<=1) s += __shfl_xor(s, off);
  if ((t&63)==0) sred2[row][t>>6]=s;
  __syncthreads();
  float var=(sred2[row][0]+sred2[row][1])*(1.f/HCH);
  float xh = d*rsqrtf(var+1e-5f)*cvt[O_LN1G+t] + cvt[O_LN1B+t];
  x2[row][t]=xh; lf[rb*HCH+t]=xh;
  __syncthreads();
  const float* WKlt = wt + 4*16384;
  const float* WVlt = wt + 5*16384;
  float aK=0.f, aV=0.f;
  for (int c=0;c<HCH;c++){
    float xc=x2[row][c];
    aK += xc*WKlt[c*128+t];
    aV += xc*WVlt[c*128+t];
  }
  Klw16[rb*HCH+t]=__float2bfloat16(aK);
  Vlw16[rb*HCH+t]=__float2bfloat16(aV);
}

// ------------------------------------------------- k3: fused residue-edge, XCD-swizzled, b64 LDS reads
__global__ __launch_bounds__(256) void k3_edge(
    const float* __restrict__ cvt, const int* __restrict__ res_S, const int* __restrict__ nbr,
    const bf16* __restrict__ Qw16, const bf16* __restrict__ Kw16,
    const bf16* __restrict__ TQw16, const bf16* __restrict__ TKw16,
    const bf16* __restrict__ Vw16, const float* __restrict__ cT, const float* __restrict__ sigT,
    float* __restrict__ r_ws, bf16* __restrict__ aVe16, float* __restrict__ dXe)
{
  __shared__ unsigned Bq[14*66], Bk[14*66], Tq[14*66], Tk[14*66];
  __shared__ float LG[784], FR[196];
  __shared__ float tw2s[128], tb2s[1], Xr[42], Xc[42], amr[14], amc[14], rpart[56], cnts[2];
  unsigned* Vc = Tq;   // Tq dead after logits/fa phase

  int b = blockIdx.x, tid = threadIdx.x;
  int rr = b & 255, slot = b >> 8;
  int e  = (slot < 8) ? (rr*8 + slot) : (2048 + rr);
  int cc = (slot < 8) ? (nbr[rr*8 + slot] & 255) : rr;

  const unsigned* Q32  = (const unsigned*)Qw16;
  const unsigned* K32  = (const unsigned*)Kw16;
  const unsigned* TQ32 = (const unsigned*)TQw16;
  const unsigned* TK32 = (const unsigned*)TKw16;
  const unsigned* V32  = (const unsigned*)Vw16;

  for (int i=tid;i<NCA*64;i+=256){
    int p=i>>6, k=i&63;
    Bq[p*66+k]=Q32[rr*896+i];  Bk[p*66+k]=K32[cc*896+i];
    Tq[p*66+k]=TQ32[rr*896+i]; Tk[p*66+k]=TK32[cc*896+i];
  }
  if (tid < 128) tw2s[tid]=cvt[O_TIW2+tid];
  if (tid == 128) tb2s[0]=cvt[O_TIB2];
  if (tid >= 136 && tid < 178){
    int i=tid-136; int p=i/3, jx=i%3;
    Xr[i] = cvt[O_RESX+(rr*NCA+p)*3+jx];
    Xc[i] = cvt[O_RESX+(cc*NCA+p)*3+jx];
  }
  if (tid >= 242 && tid < 242+NCA){
    int p=tid-242;
    amr[p] = (p < ccount(res_S[rr])) ? 1.f : 0.f;
    amc[p] = (p < ccount(res_S[cc])) ? 1.f : 0.f;
  }
  __syncthreads();

  if (tid < 196){
    int p = tid/14, q = tid%14;
    float dx=Xr[p*3]-Xc[q*3], dy=Xr[p*3+1]-Xc[q*3+1], dz=Xr[p*3+2]-Xc[q*3+2];
    float d = sqrtf(fmaxf(dx*dx+dy*dy+dz*dz, 1e-12f));
    int i0 = (int)(fminf(d, DMAXT)*TSCALE + 0.5f);
    float4 sg = ((const float4*)sigT)[i0];
    const float4* crow = (const float4*)(cT + i0*128);
    const uint2* Tq2 = (const uint2*)Tq;
    const uint2* Tk2 = (const uint2*)Tk;
    const uint2* Bq2 = (const uint2*)Bq;
    const uint2* Bk2 = (const uint2*)Bk;
    float fa = tb2s[0];
    #pragma unroll 8
    for (int j=0;j<32;j++){
      float4 cb = crow[j];
      uint2 ta = Tq2[p*33 + j];
      uint2 ka = Tk2[q*33 + j];
      int o = 4*j;
      fa += fmaxf(bflo(ta.x)+bflo(ka.x)+cb.x, 0.f)*tw2s[o  ];
      fa += fmaxf(bfhi(ta.x)+bfhi(ka.x)+cb.y, 0.f)*tw2s[o+1];
      fa += fmaxf(bflo(ta.y)+bflo(ka.y)+cb.z, 0.f)*tw2s[o+2];
      fa += fmaxf(bfhi(ta.y)+bfhi(ka.y)+cb.w, 0.f)*tw2s[o+3];
    }
    float qk0=0,qk1=0,qk2=0,qk3=0;
    #pragma unroll
    for (int j=0;j<8;j++){
      uint2 a0=Bq2[p*33+j],    b0=Bk2[q*33+j];
      uint2 a1=Bq2[p*33+8+j],  b1=Bk2[q*33+8+j];
      uint2 a2=Bq2[p*33+16+j], b2=Bk2[q*33+16+j];
      uint2 a3=Bq2[p*33+24+j], b3=Bk2[q*33+24+j];
      qk0 += bflo(a0.x)*bflo(b0.x) + bfhi(a0.x)*bfhi(b0.x) + bflo(a0.y)*bflo(b0.y) + bfhi(a0.y)*bfhi(b0.y);
      qk1 += bflo(a1.x)*bflo(b1.x) + bfhi(a1.x)*bfhi(b1.x) + bflo(a1.y)*bflo(b1.y) + bfhi(a1.y)*bfhi(b1.y);
      qk2 += bflo(a2.x)*bflo(b2.x) + bfhi(a2.x)*bfhi(b2.x) + bflo(a2.y)*bflo(b2.y) + bfhi(a2.y)*bfhi(b2.y);
      qk3 += bflo(a3.x)*bflo(b3.x) + bfhi(a3.x)*bfhi(b3.x) + bflo(a3.y)*bflo(b3.y) + bfhi(a3.y)*bfhi(b3.y);
    }
    const float isq = 0.17677669529663687f;
    LG[0*196+tid] = qk0*isq + sg.x;
    LG[1*196+tid] = qk1*isq + sg.y;
    LG[2*196+tid] = qk2*isq + sg.z;
    LG[3*196+tid] = qk3*isq + sg.w;
    FR[tid] = fa;
  }
  __syncthreads();   // Tq dead; Vc alias staged next

  for (int i=tid;i<NCA*64;i+=256){
    int p=i>>6, k=i&63;
    Vc[p*66+k]=V32[cc*896+i];
  }
  if (tid < 56){
    int h=tid/14, pp=tid%14;
    float ap = amr[pp];
    float row[NCA];
    float s=0;
    #pragma unroll
    for (int qq=0;qq<NCA;qq++){ row[qq]=LG[h*196+pp*14+qq]; s += row[qq]*amc[qq]; }
    rpart[h*14+pp] = s*ap;
    float m=-INFINITY;
    #pragma unroll
    for (int qq=0;qq<NCA;qq++) m=fmaxf(m,row[qq]);
    float sum=0;
    #pragma unroll
    for (int qq=0;qq<NCA;qq++){ row[qq]=expf(row[qq]-m); sum+=row[qq]; }
    float inv=1.f/sum, s2=0;
    #pragma unroll
    for (int qq=0;qq<NCA;qq++){ row[qq]=row[qq]*inv*ap*amc[qq]; s2+=row[qq]; }
    float inv2=1.f/(s2+1e-7f);
    #pragma unroll
    for (int qq=0;qq<NCA;qq++) LG[h*196+pp*14+qq]=row[qq]*inv2;
  }
  if (tid == 56){
    float sr=0, sc=0;
    for (int i=0;i<NCA;i++){ sr+=amr[i]; sc+=amc[i]; }
    cnts[0]=sr; cnts[1]=sc;
  }
  __syncthreads();
  if (tid < NH){
    float s=0;
    for (int pp=0;pp<NCA;pp++) s += rpart[tid*14+pp];
    r_ws[e*NH+tid] = s/(cnts[0]*cnts[1]);
  }
  if (tid < 196){
    int p=tid/14, q=tid%14;
    float ma = 0.25f*(LG[p*14+q] + LG[196+p*14+q] + LG[392+p*14+q] + LG[588+p*14+q]);
    FR[tid] *= ma;
  }
  __syncthreads();
  if (tid < NCA){
    int pp=tid;
    float ax=0, ay=0, az=0;
    #pragma unroll
    for (int qq=0;qq<NCA;qq++){
      float dx=Xr[pp*3]-Xc[qq*3], dy=Xr[pp*3+1]-Xc[qq*3+1], dz=Xr[pp*3+2]-Xc[qq*3+2];
      float nrm = sqrtf(fmaxf(dx*dx+dy*dy+dz*dz,1e-12f));
      float sc = FR[pp*14+qq]/(nrm+1e-5f);
      ax += sc*dx; ay += sc*dy; az += sc*dz;
    }
    dXe[(e*NCA+pp)*3+0]=ax; dXe[(e*NCA+pp)*3+1]=ay; dXe[(e*NCA+pp)*3+2]=az;
  }
  // aV: 896 packed u32 outputs (2 dd per thread-job)
  unsigned* aVe32 = (unsigned*)aVe16;
  #pragma unroll
  for (int rep=0;rep<4;rep++){
    int jdx = rep*256 + tid;
    if (jdx < 896){
      int h = jdx/224, rem = jdx%224;
      int pp = rem>>4, ddp = rem&15;
      float a0=0, a1=0;
      #pragma unroll
      for (int qq=0;qq<NCA;qq++){
        unsigned v = Vc[qq*66 + h*16 + ddp];
        float l = LG[h*196+pp*14+qq];
        a0 += l*bflo(v);
        a1 += l*bfhi(v);
      }
      aVe32[e*896 + jdx] = pack2(a0,a1);
    }
  }
}

// ------------------------------------------------- k4: per-residue beta + updH + WO + dX (256 threads)
__global__ __launch_bounds__(256) void k4_agg(
    const float* __restrict__ cvt, const int* __restrict__ res_S, const int* __restrict__ inv_row,
    const float* __restrict__ r_ws, const bf16* __restrict__ aVe16, const float* __restrict__ dXe,
    const float* __restrict__ resHn, const float* __restrict__ wt, const int* __restrict__ flag,
    float* __restrict__ resH2, float* __restrict__ resX2, void* __restrict__ d_out)
{
  int n = blockIdx.x, tid = threadIdx.x;
  __shared__ float beta[9][NH];
  __shared__ float betam[9];
  __shared__ float Xs[NCA][HCH];
  if (tid < NH){
    int h = tid;
    float rv[9], m=-INFINITY;
    #pragma unroll
    for (int k=0;k<9;k++){
      int ek = (k<KNNK)? n*KNNK+k : NKE+n;
      rv[k] = r_ws[ek*NH+h];
      m = fmaxf(m, rv[k]);
    }
    float s=0;
    #pragma unroll
    for (int k=0;k<9;k++){ rv[k]=expf(rv[k]-m); s+=rv[k]; }
    #pragma unroll
    for (int k=0;k<9;k++) beta[k][h]=rv[k]/s;
  }
  __syncthreads();
  if (tid < 9) betam[tid] = 0.25f*(beta[tid][0]+beta[tid][1]+beta[tid][2]+beta[tid][3]);
  int col = tid & 127, ph = tid >> 7;
  int h = col>>5, dd = col&31;
  float bh[9];
  #pragma unroll
  for (int k=0;k<9;k++) bh[k]=beta[k][h];
  #pragma unroll
  for (int i=0;i<7;i++){
    int p = ph + 2*i;
    float u=0;
    #pragma unroll
    for (int k=0;k<9;k++){
      int ek = (k<KNNK)? n*KNNK+k : NKE+n;
      u += bh[k]*b2f(aVe16[ek*1792 + h*448 + p*32 + dd]);
    }
    Xs[p][col] = sspf(u);
  }
  __syncthreads();
  const float* WOt = wt + 3*16384;
  float acc[7];
  #pragma unroll
  for (int i=0;i<7;i++) acc[i]=0.f;
  for (int c=0;c<HCH;c++){
    float w = WOt[c*128+col];
    #pragma unroll
    for (int i=0;i<7;i++) acc[i] += Xs[ph+2*i][c]*w;
  }
  int cnt = ccount(res_S[n]);
  #pragma unroll
  for (int i=0;i<7;i++){
    int p = ph + 2*i;
    float am = (p<cnt)?1.f:0.f;
    float outv = (resHn[(n*NCA+p)*HCH+col] + acc[i])*am;
    resH2[(n*NCA+p)*HCH+col] = outv;
  }
  if (tid < NCA*3){
    int isbf = *flag;
    int p=tid/3, jx=tid%3;
    float s=0;
    #pragma unroll
    for (int k=0;k<9;k++){
      int ek=(k<KNNK)? n*KNNK+k : NKE+n;
      s += betam[k]*dXe[(ek*NCA+p)*3+jx];
    }
    float base = cvt[O_RESX+(n*NCA+p)*3+jx];
    float v = (inv_row[n]>=0) ? base + fminf(fmaxf(s,-3.f),3.f) : base;
    resX2[(n*NCA+p)*3+jx] = v;
    storeOut(d_out, isbf, OUTX_OFF + (n*NCA+p)*3+jx, v);
  }
}

// ------------------------------------------------- k6: fused ligand-edge (logits + softmaxes + aVr/aVlg)
__global__ __launch_bounds__(256) void k6_lig(
    const float* __restrict__ cvt, const int* __restrict__ res_S,
    const int* __restrict__ row1, const int* __restrict__ col1,
    const float* __restrict__ resX2, const bf16* __restrict__ Qw16, const bf16* __restrict__ Klw16,
    const bf16* __restrict__ Vw16, const bf16* __restrict__ Vlw16, const float* __restrict__ sig1T,
    float* __restrict__ r1_ws, float* __restrict__ aVr, float* __restrict__ aVlg)
{
  __shared__ __align__(16) float S[10042];
  float* Bq  = S;
  float* Bk  = S + 1848;
  float* LG  = S;
  float* Vl  = S + 1848;
  float* ALs = S + 6104;
  float* Vr  = S + 7896;
  float* EX  = S + 9744;
  float* Xr = EX;
  float* Lp = EX + 42;
  float* amr = EX + 138;
  float* lm  = EX + 152;
  float* s2r = EX + 184;
  float* rpart = EX + 240;
  float* cnts  = EX + 296;
  int e = blockIdx.x, tid = threadIdx.x;
  int rr = row1[e] & 255, cb = col1[e] & 3;

  for (int i=tid;i<NCA*HCH;i+=256){ int p=i>>7,c=i&127; Bq[p*132+c]=b2f(Qw16[rr*1792+i]); Vr[p*132+c]=b2f(Vw16[rr*1792+i]); }
  for (int i=tid;i<LC*HCH;i+=256){ int q=i>>7,c=i&127; Bk[q*133+c]=b2f(Klw16[cb*LC*HCH+i]); }
  if (tid >= 8 && tid < 50){ int i=tid-8; int p=i/3,jx=i%3; Xr[i]=resX2[(rr*NCA+p)*3+jx]; }
  if (tid >= 64 && tid < 160){ int i=tid-64; int q=i/3,jx=i%3; Lp[i]=cvt[O_LPOS+(cb*LC+q)*3+jx]; }
  if (tid >= 160 && tid < 160+NCA) amr[tid-160]=((tid-160) < ccount(res_S[rr]))?1.f:0.f;
  if (tid >= 192 && tid < 224) lm[tid-192]=cvt[O_LMASK + cb*LC + tid-192];
  __syncthreads();

  float l0[2][4];
  int npair = (tid < 192) ? 2 : 1;
  for (int w=0; w<npair; w++){
    int pair = tid + w*256;
    int p = pair>>5, q = pair&31;
    float dx=Xr[p*3]-Lp[q*3], dy=Xr[p*3+1]-Lp[q*3+1], dz=Xr[p*3+2]-Lp[q*3+2];
    float d = sqrtf(fmaxf(dx*dx+dy*dy+dz*dz,1e-12f));
    int i0 = (int)(fminf(d, DMAXT)*TSCALE + 0.5f);
    float4 sg = ((const float4*)sig1T)[i0];
    float q0=0,q1=0,q2=0,q3=0;
    #pragma unroll
    for (int dd=0;dd<DH;dd++){
      q0 += Bq[p*132+dd]   *Bk[q*133+dd];
      q1 += Bq[p*132+32+dd]*Bk[q*133+32+dd];
      q2 += Bq[p*132+64+dd]*Bk[q*133+64+dd];
      q3 += Bq[p*132+96+dd]*Bk[q*133+96+dd];
    }
    const float isq=0.17677669529663687f;
    l0[w][0]=q0*isq+sg.x; l0[w][1]=q1*isq+sg.y; l0[w][2]=q2*isq+sg.z; l0[w][3]=q3*isq+sg.w;
  }
  __syncthreads();
  for (int w=0; w<npair; w++){
    int pair = tid + w*256;
    LG[0*448+pair]=l0[w][0]; LG[1*448+pair]=l0[w][1]; LG[2*448+pair]=l0[w][2]; LG[3*448+pair]=l0[w][3];
  }
  for (int i=tid;i<LC*HCH;i+=256){ int q=i>>7,c=i&127; Vl[q*132+c]=b2f(Vlw16[cb*LC*HCH+i]); }
  __syncthreads();

  if (tid < 56){
    int h=tid/14, pp=tid%14;
    float ap=amr[pp];
    float s=0, m=-INFINITY;
    for (int qq=0;qq<LC;qq++){ float v=LG[h*448+pp*32+qq]; s+=v*lm[qq]; m=fmaxf(m,v); }
    rpart[h*14+pp]=s*ap;
    float sum=0;
    for (int qq=0;qq<LC;qq++) sum+=expf(LG[h*448+pp*32+qq]-m);
    float inv=1.f/sum, s2=0;
    for (int qq=0;qq<LC;qq++) s2 += expf(LG[h*448+pp*32+qq]-m)*inv*ap*lm[qq];
    s2r[h*14+pp] = s2/(s2+1e-7f);
  }
  if (tid==56){
    float sr=0,sl=0;
    for(int i=0;i<NCA;i++) sr+=amr[i];
    for(int i=0;i<LC;i++) sl+=lm[i];
    cnts[0]=sr; cnts[1]=sl;
  }
  __syncthreads();
  if (tid < NH){
    float s=0; for (int pp=0;pp<NCA;pp++) s+=rpart[tid*14+pp];
    r1_ws[e*NH+tid]=s/(cnts[0]*cnts[1]);
  }
  if (tid < NH*LC){
    int h=tid>>5, qq=tid&31;
    float m=-INFINITY;
    for (int pp=0;pp<NCA;pp++) m=fmaxf(m,LG[h*448+pp*32+qq]);
    float sum=0;
    for (int pp=0;pp<NCA;pp++) sum+=expf(LG[h*448+pp*32+qq]-m);
    float inv=1.f/sum;
    float lq=lm[qq];
    for (int pp=0;pp<NCA;pp++){
      float a=expf(LG[h*448+pp*32+qq]-m)*inv*amr[pp]*lq;
      ALs[h*448+pp*32+qq]=a/(s2r[h*14+pp]+1e-7f);
    }
  }
  __syncthreads();
  if (tid < 56){
    int h=tid/14, pp=tid%14;
    float ap=amr[pp];
    float m=-INFINITY;
    for (int qq=0;qq<LC;qq++) m=fmaxf(m,LG[h*448+pp*32+qq]);
    float row[LC];
    float sum=0;
    for (int qq=0;qq<LC;qq++){ row[qq]=expf(LG[h*448+pp*32+qq]-m); sum+=row[qq]; }
    float inv=1.f/sum, s2=0;
    for (int qq=0;qq<LC;qq++){ row[qq]=row[qq]*inv*ap*lm[qq]; s2+=row[qq]; }
    float inv2=1.f/(s2+1e-7f);
    for (int qq=0;qq<LC;qq++) LG[h*448+pp*32+qq]=row[qq]*inv2;
  }
  __syncthreads();
  for (int j=tid;j<NH*NCA*DH;j+=256){
    int h=j/448, rem=j%448, pp=rem>>5, dd=rem&31;
    float acc=0;
    #pragma unroll
    for (int qq=0;qq<LC;qq++) acc += LG[h*448+pp*32+qq]*Vl[qq*132+h*32+dd];
    aVr[e*1792+j]=acc;
  }
  for (int j=tid;j<NH*LC*DH;j+=256){
    int h=j>>10, rem=j&1023, qq=rem>>5, dd=rem&31;
    float acc=0;
    #pragma unroll
    for (int pp=0;pp<NCA;pp++) acc += ALs[h*448+pp*32+qq]*Vr[pp*132+h*32+dd];
    aVlg[e*4096+j]=acc;
  }
}

// ------------------------------------------------- k78: finalize res_H3 (0..255, 256 thr) + lf2 (256..383)
__global__ __launch_bounds__(256) void k78_final(
    const int* __restrict__ inv_row, const int* __restrict__ res_S, const int* __restrict__ col1,
    const float* __restrict__ resH2, const float* __restrict__ aVr,
    const float* __restrict__ r1_ws, const float* __restrict__ aVlg, const float* __restrict__ lf,
    const float* __restrict__ wt, const int* __restrict__ flag, void* __restrict__ d_out)
{
  int bb = blockIdx.x, tid = threadIdx.x;
  if (bb < 256){
    int n = bb;
    int e = inv_row[n];
    __shared__ float G[NCA][HCH];
    if (e>=0){
      for (int j=tid;j<NCA*HCH;j+=256){
        int h=j/448, rem=j%448, pp=rem>>5, dd=rem&31;
        G[pp][h*DH+dd] = sspf(aVr[e*1792+j]);
      }
    }
    __syncthreads();
    int col = tid & 127, ph = tid >> 7;
    float acc[7];
    #pragma unroll
    for (int i=0;i<7;i++) acc[i]=0.f;
    if (e>=0){
      const float* WOlt = wt + 6*16384;
      for (int c=0;c<HCH;c++){
        float w=WOlt[c*128+col];
        #pragma unroll
        for (int i=0;i<7;i++) acc[i]+=G[ph+2*i][c]*w;
      }
    }
    int cnt=ccount(res_S[n]);
    int isbf = *flag;
    #pragma unroll
    for (int i=0;i<7;i++){
      int p = ph + 2*i;
      float am=(p<cnt)?1.f:0.f;
      float v=(resH2[(n*NCA+p)*HCH+col]+acc[i])*am;
      storeOut(d_out, isbf, (n*NCA+p)*HCH+col, v);
    }
    return;
  }
  // lf2 path (use 128 threads; rest idle)
  int rb = bb - 256;
  int b = rb>>5, q = rb&31;
  __shared__ float bw[NE1][NH];
  __shared__ float xs[HCH];
  if (tid<NH){
    int h=tid;
    float m=-INFINITY;
    for (int e=0;e<NE1;e++) if ((col1[e]&3)==b) m=fmaxf(m, r1_ws[e*NH+h]);
    float s=0;
    for (int e=0;e<NE1;e++) if ((col1[e]&3)==b) s+=expf(r1_ws[e*NH+h]-m);
    for (int e=0;e<NE1;e++) bw[e][h] = ((col1[e]&3)==b)? expf(r1_ws[e*NH+h]-m)/s : 0.f;
  }
  __syncthreads();
  if (tid < 128){
    int h=tid>>5, dd=tid&31;
    float u=0;
    for (int e=0;e<NE1;e++) u += bw[e][h]*aVlg[e*4096 + h*1024 + q*32 + dd];
    xs[tid]=sspf(u);
  }
  __syncthreads();
  if (tid < 128){
    const float* WOl1t = wt + 7*16384;
    float acc=0;
    for (int c=0;c<HCH;c++) acc += xs[c]*WOl1t[c*128+tid];
    float v = lf[rb*HCH+tid] + acc;
    storeOut(d_out, *flag, OUTL_OFF + rb*HCH+tid, v);
  }
}

// ================================================================ launch
extern "C" void kernel_launch(void* const* d_in, const int* in_sizes, int n_in,
                              void* d_out, int out_size, void* d_ws, size_t ws_size,
                              hipStream_t stream)
{
  const int* res_S = (const int*)d_in[29];
  const int* batch = (const int*)d_in[30];
  const int* row1  = (const int*)d_in[32];
  const int* col1  = (const int*)d_in[33];

  float* wsf = (float*)d_ws;
  size_t o = 0;
  int*   flag    = (int*)(wsf + o); o += 4;
  float* cvt     = wsf + o; o += CVT_RSV;
  float* wt      = wsf + o; o += 10*16384;
  int*   inv_row = (int*)(wsf + o); o += 256;
  int*   nbr     = (int*)(wsf + o); o += NRES*KNNK;
  float* resHn   = wsf + o; o += NROWS*HCH;
  bf16*  Qw16    = (bf16*)(wsf + o); o += NROWS*HCH/2;
  bf16*  Kw16    = (bf16*)(wsf + o); o += NROWS*HCH/2;
  bf16*  Vw16    = (bf16*)(wsf + o); o += NROWS*HCH/2;
  bf16*  TQw16   = (bf16*)(wsf + o); o += NROWS*HCH/2;
  bf16*  TKw16   = (bf16*)(wsf + o); o += NROWS*HCH/2;
  float* r_ws    = wsf + o; o += NEDGE*NH;
  bf16*  aVe16   = (bf16*)(wsf + o); o += (size_t)NEDGE*1792/2;
  float* dXe     = wsf + o; o += NEDGE*NCA*3;
  float* resH2   = wsf + o; o += NROWS*HCH;
  float* resX2   = wsf + o; o += NRES*NCA*3;
  float* lf      = wsf + o; o += 4*LC*HCH;
  bf16*  Klw16   = (bf16*)(wsf + o); o += 4*LC*HCH/2;
  bf16*  Vlw16   = (bf16*)(wsf + o); o += 4*LC*HCH/2;
  float* r1w     = wsf + o; o += NE1*NH;
  float* aVrw    = wsf + o; o += NE1*1792;
  float* aVlgw   = wsf + o; o += NE1*4096;
  float* cT      = wsf + o; o += (size_t)NT*128;
  float* sigT    = wsf + o; o += NT*4;
  float* sig1T   = wsf + o; o += NT*4;

  kcvt<<<(TOTCVT+255)/256, 256, 0, stream>>>(
      d_in[0],d_in[1],d_in[2],d_in[3],d_in[4],d_in[5],d_in[6],d_in[7],d_in[8],
      d_in[9],d_in[10],d_in[11],d_in[12],d_in[13],d_in[14],d_in[15],d_in[16],
      d_in[17],d_in[18],d_in[19],d_in[20],d_in[21],d_in[22],d_in[23],d_in[24],
      d_in[25],d_in[26],d_in[27],d_in[28], cvt, flag);
  kprep<<<NT + 1280 + 1, 128, 0, stream>>>(cvt, row1, cT, sigT, sig1T, wt, inv_row);
  kProjAll<<<800, 256, 0, stream>>>(cvt, wt, batch, resHn, Qw16, Kw16, Vw16, TQw16, TKw16,
                                    nbr, lf, Klw16, Vlw16);
  k3_edge<<<NEDGE, 256, 0, stream>>>(cvt, res_S, nbr, Qw16, Kw16, TQw16, TKw16, Vw16, cT, sigT,
                                     r_ws, aVe16, dXe);
  k4_agg<<<NRES, 256, 0, stream>>>(cvt, res_S, inv_row, r_ws, aVe16, dXe, resHn, wt, flag,
                                   resH2, resX2, d_out);
  k6_lig<<<NE1, 256, 0, stream>>>(cvt, res_S, row1, col1, resX2, Qw16, Klw16, Vw16, Vlw16, sig1T,
                                  r1w, aVrw, aVlgw);
  k78_final<<<384, 256, 0, stream>>>(inv_row, res_S, col1, resH2, aVrw, r1w, aVlgw, lf,
                                     wt, flag, d_out);
}